// Round 4
// baseline (500.880 us; speedup 1.0000x reference)
//
#include <hip/hip_runtime.h>
#include <cstdint>

#define HIDDEN 2048
#define NHEADS 16
#define DH 128
#define BATCH 2
#define SEQ 2048
#define MTOT 4096
#define BH (BATCH * NHEADS)

typedef __attribute__((ext_vector_type(8))) short bf16x8;
typedef __attribute__((ext_vector_type(4))) float f32x4;

// SCALE * log2(e): scores come out of QK^T already in log2 domain
static constexpr float QSCALE = (float)(0.08838834764831845 * 1.4426950408889634);

__device__ __forceinline__ unsigned short f2bf(float f) {
  union { float f; uint32_t u; } v; v.f = f;
  uint32_t r = v.u + 0x7FFFu + ((v.u >> 16) & 1u);
  return (unsigned short)(r >> 16);
}
__device__ __forceinline__ float bf2f(unsigned short h) {
  union { uint32_t u; float f; } v; v.u = ((uint32_t)h) << 16;
  return v.f;
}
__device__ __forceinline__ uint32_t cvtpk(float lo, float hi) {
  uint32_t r;
  asm("v_cvt_pk_bf16_f32 %0, %1, %2" : "=v"(r) : "v"(lo), "v"(hi));
  return r;
}
__device__ __forceinline__ f32x4 mfma16(bf16x8 a, bf16x8 b, f32x4 c) {
  return __builtin_amdgcn_mfma_f32_16x16x32_bf16(a, b, c, 0, 0, 0);
}

typedef const __attribute__((address_space(1))) unsigned char* gas1_t;
typedef __attribute__((address_space(3))) unsigned char* las3_t;
__device__ __forceinline__ void gll16(const void* g, void* l) {
  __builtin_amdgcn_global_load_lds((gas1_t)g, (las3_t)l, 16, 0, 0);
}

// ---------------------------------------------------------------------------
// casts
// ---------------------------------------------------------------------------
__global__ __launch_bounds__(256) void cast_bf16_kernel(const float* __restrict__ in,
                                                        unsigned short* __restrict__ out,
                                                        int n) {
  int i = (blockIdx.x * 256 + threadIdx.x) * 4;
  if (i < n) {
    float4 f = *(const float4*)&in[i];
    ushort4 o;
    o.x = f2bf(f.x); o.y = f2bf(f.y); o.z = f2bf(f.z); o.w = f2bf(f.w);
    *(ushort4*)&out[i] = o;
  }
}

__global__ __launch_bounds__(256) void cast_split_kernel(const float* __restrict__ in,
                                                         unsigned short* __restrict__ hi,
                                                         unsigned short* __restrict__ lo,
                                                         int n) {
  int i = (blockIdx.x * 256 + threadIdx.x) * 4;
  if (i < n) {
    float4 f = *(const float4*)&in[i];
    ushort4 h, l;
    h.x = f2bf(f.x); l.x = f2bf(f.x - bf2f(h.x));
    h.y = f2bf(f.y); l.y = f2bf(f.y - bf2f(h.y));
    h.z = f2bf(f.z); l.z = f2bf(f.z - bf2f(h.z));
    h.w = f2bf(f.w); l.w = f2bf(f.w - bf2f(h.w));
    *(ushort4*)&hi[i] = h;
    *(ushort4*)&lo[i] = l;
  }
}

// ---------------------------------------------------------------------------
// bf16 GEMM, m97 structure (unchanged from round 3).
// MODE 0: Q layout [BH][S][D];  MODE 1: K blocked [BH][S/32][d/8][s%32][8]
// MODE 2: V blocked [BH][S/8][D][8]
// ---------------------------------------------------------------------------
template <int MODE>
__global__ __launch_bounds__(256) void gemm_qkv(const unsigned short* __restrict__ A,
                                                const unsigned short* __restrict__ W,
                                                unsigned short* __restrict__ C,
                                                float alpha) {
  __shared__ __align__(16) unsigned short As[4096];
  __shared__ __align__(16) unsigned short Ws[4096];
  const int tid = threadIdx.x;
  const int lane = tid & 63, wv = tid >> 6;
  const int wr = wv >> 1, wc = wv & 1;
  const int g = lane >> 4, lr = lane & 15;
  const int m0 = blockIdx.y * 128, n0 = blockIdx.x * 128;

  f32x4 acc[4][4];
#pragma unroll
  for (int i = 0; i < 4; ++i)
#pragma unroll
    for (int j = 0; j < 4; ++j) acc[i][j] = (f32x4){0.f, 0.f, 0.f, 0.f};

  const int c0 = tid, c1 = 256 + tid;
  const int row0 = c0 >> 2, kb0 = (c0 & 3) ^ ((row0 >> 1) & 3);
  const int row1 = c1 >> 2, kb1 = (c1 & 3) ^ ((row1 >> 1) & 3);
  const size_t aoff0 = (size_t)(m0 + row0) * HIDDEN + kb0 * 8;
  const size_t aoff1 = (size_t)(m0 + row1) * HIDDEN + kb1 * 8;
  const size_t woff0 = (size_t)(n0 + row0) * HIDDEN + kb0 * 8;
  const size_t woff1 = (size_t)(n0 + row1) * HIDDEN + kb1 * 8;
  const int swz = ((lr >> 1) & 3) * 16;

  for (int k0 = 0; k0 < HIDDEN; k0 += 32) {
    __syncthreads();
    gll16(A + aoff0 + k0, (char*)As + wv * 1024);
    gll16(W + woff0 + k0, (char*)Ws + wv * 1024);
    gll16(A + aoff1 + k0, (char*)As + 4096 + wv * 1024);
    gll16(W + woff1 + k0, (char*)Ws + 4096 + wv * 1024);
    __syncthreads();

    bf16x8 af[4], wf[4];
#pragma unroll
    for (int mi = 0; mi < 4; ++mi) {
      const int row = wr * 64 + mi * 16 + lr;
      af[mi] = *(const bf16x8*)((const char*)As + row * 64 + ((g * 16) ^ swz));
    }
#pragma unroll
    for (int ni = 0; ni < 4; ++ni) {
      const int row = wc * 64 + ni * 16 + lr;
      wf[ni] = *(const bf16x8*)((const char*)Ws + row * 64 + ((g * 16) ^ swz));
    }
#pragma unroll
    for (int mi = 0; mi < 4; ++mi)
#pragma unroll
      for (int ni = 0; ni < 4; ++ni)
        acc[mi][ni] = mfma16(af[mi], wf[ni], acc[mi][ni]);
  }

#pragma unroll
  for (int mi = 0; mi < 4; ++mi)
#pragma unroll
    for (int ni = 0; ni < 4; ++ni)
#pragma unroll
      for (int r = 0; r < 4; ++r) {
        const int row = m0 + wr * 64 + mi * 16 + g * 4 + r;
        const int col = n0 + wc * 64 + ni * 16 + lr;
        const unsigned short v = f2bf(acc[mi][ni][r] * alpha);
        const int b = row >> 11, s = row & (SEQ - 1);
        const int h = col >> 7, d = col & (DH - 1);
        const size_t base = (size_t)(b * NHEADS + h) * SEQ * DH;
        if (MODE == 0)
          C[base + (size_t)s * DH + d] = v;
        else if (MODE == 1)
          C[base + (size_t)(s >> 5) * 4096 + (d >> 3) * 256 + (s & 31) * 8 + (d & 7)] = v;
        else
          C[base + (size_t)(s >> 3) * 1024 + d * 8 + (s & 7)] = v;
      }
}

// ---------------------------------------------------------------------------
// Split-bf16x2 O-proj (unchanged from round 3)
// ---------------------------------------------------------------------------
__global__ __launch_bounds__(256) void gemm_osplit(const unsigned short* __restrict__ A,
                                                   const unsigned short* __restrict__ Wh,
                                                   const unsigned short* __restrict__ Wl,
                                                   float* __restrict__ C) {
  __shared__ __align__(16) unsigned short As[4096];
  __shared__ __align__(16) unsigned short Whs[4096];
  __shared__ __align__(16) unsigned short Wls[4096];
  const int tid = threadIdx.x;
  const int lane = tid & 63, wv = tid >> 6;
  const int wr = wv >> 1, wc = wv & 1;
  const int g = lane >> 4, lr = lane & 15;
  const int m0 = blockIdx.y * 128, n0 = blockIdx.x * 128;

  f32x4 acc[4][4];
#pragma unroll
  for (int i = 0; i < 4; ++i)
#pragma unroll
    for (int j = 0; j < 4; ++j) acc[i][j] = (f32x4){0.f, 0.f, 0.f, 0.f};

  const int c0 = tid, c1 = 256 + tid;
  const int row0 = c0 >> 2, kb0 = (c0 & 3) ^ ((row0 >> 1) & 3);
  const int row1 = c1 >> 2, kb1 = (c1 & 3) ^ ((row1 >> 1) & 3);
  const size_t aoff0 = (size_t)(m0 + row0) * HIDDEN + kb0 * 8;
  const size_t aoff1 = (size_t)(m0 + row1) * HIDDEN + kb1 * 8;
  const size_t woff0 = (size_t)(n0 + row0) * HIDDEN + kb0 * 8;
  const size_t woff1 = (size_t)(n0 + row1) * HIDDEN + kb1 * 8;
  const int swz = ((lr >> 1) & 3) * 16;

  for (int k0 = 0; k0 < HIDDEN; k0 += 32) {
    __syncthreads();
    gll16(A + aoff0 + k0, (char*)As + wv * 1024);
    gll16(Wh + woff0 + k0, (char*)Whs + wv * 1024);
    gll16(Wl + woff0 + k0, (char*)Wls + wv * 1024);
    gll16(A + aoff1 + k0, (char*)As + 4096 + wv * 1024);
    gll16(Wh + woff1 + k0, (char*)Whs + 4096 + wv * 1024);
    gll16(Wl + woff1 + k0, (char*)Wls + 4096 + wv * 1024);
    __syncthreads();

    bf16x8 af[4], wfh[4], wfl[4];
#pragma unroll
    for (int mi = 0; mi < 4; ++mi) {
      const int row = wr * 64 + mi * 16 + lr;
      af[mi] = *(const bf16x8*)((const char*)As + row * 64 + ((g * 16) ^ swz));
    }
#pragma unroll
    for (int ni = 0; ni < 4; ++ni) {
      const int row = wc * 64 + ni * 16 + lr;
      wfh[ni] = *(const bf16x8*)((const char*)Whs + row * 64 + ((g * 16) ^ swz));
      wfl[ni] = *(const bf16x8*)((const char*)Wls + row * 64 + ((g * 16) ^ swz));
    }
#pragma unroll
    for (int mi = 0; mi < 4; ++mi)
#pragma unroll
      for (int ni = 0; ni < 4; ++ni) {
        acc[mi][ni] = mfma16(af[mi], wfh[ni], acc[mi][ni]);
        acc[mi][ni] = mfma16(af[mi], wfl[ni], acc[mi][ni]);
      }
  }

#pragma unroll
  for (int mi = 0; mi < 4; ++mi)
#pragma unroll
    for (int ni = 0; ni < 4; ++ni)
#pragma unroll
      for (int r = 0; r < 4; ++r) {
        const int row = m0 + wr * 64 + mi * 16 + g * 4 + r;
        const int col = n0 + wc * 64 + ni * 16 + lr;
        C[(size_t)row * HIDDEN + col] = acc[mi][ni][r];
      }
}

// ---------------------------------------------------------------------------
// MFMA flash attention v2: 512 thr = 8 waves. Waves 0-3 process keys
// [0,1024), waves 4-7 keys [1024,2048) for the SAME 128 q-rows (KV-split ->
// 4096 waves total = 4 waves/SIMD). Per group: KVBLK=32, double-buffered
// 8KB K + 8KB V staged via global_load_lds. Flash-combine of the two
// partials through LDS at the end. Log2-domain softmax, defer-max,
// per-lane deferred lrun, setprio around MFMA clusters.
// LDS map (bytes): K [grp][buf] @ grp*16384+buf*8192 (32KB)
//                  V @ 32768 + grp*16384 + buf*8192  (32KB)
//                  Pw @ 65536 + w*1280 (10KB); ML @ 75776 (1KB)
//                  merge acc buffer overlays [0,65536)
// ---------------------------------------------------------------------------
__global__ __launch_bounds__(512, 4) void attn_mfma(const unsigned short* __restrict__ Q,
                                                    const unsigned short* __restrict__ K,
                                                    const unsigned short* __restrict__ V,
                                                    unsigned short* __restrict__ Ab) {
  const int L = blockIdx.x;
  const int bh = (L & 7) + 8 * (L >> 7);          // XCD-swizzle: same bh -> same XCD
  const int q0 = ((L >> 3) & 15) * 128;
  const int tid = threadIdx.x;
  const int w = tid >> 6, lane = tid & 63;
  const int grp = w >> 2, wq = w & 3;
  const int g = lane >> 4, lr = lane & 15;

  const unsigned short* Qh = Q + (size_t)bh * SEQ * DH;
  const unsigned short* Kg = K + (size_t)bh * SEQ * DH + (size_t)grp * (SEQ / 2) * DH;
  const unsigned short* Vg = V + (size_t)bh * SEQ * DH + (size_t)grp * (SEQ / 2) * DH;

  __shared__ __align__(16) unsigned char SM[76800];
  unsigned short* Pwme = (unsigned short*)(SM + 65536 + w * 1280);  // [16][40]

  // Q fragments (row-major global)
  bf16x8 qf[2][4];
#pragma unroll
  for (int m = 0; m < 2; ++m)
#pragma unroll
    for (int kb = 0; kb < 4; ++kb)
      qf[m][kb] = *(const bf16x8*)&Qh[(size_t)(q0 + wq * 32 + m * 16 + lr) * DH +
                                      kb * 32 + g * 8];

  f32x4 acc[2][8];
#pragma unroll
  for (int m = 0; m < 2; ++m)
#pragma unroll
    for (int dn = 0; dn < 8; ++dn) acc[m][dn] = (f32x4){0.f, 0.f, 0.f, 0.f};
  float mrun[2] = {-1e30f, -1e30f};
  float lrun[2] = {0.f, 0.f};

  char* Kbuf = (char*)SM + grp * 16384;
  char* Vbuf = (char*)SM + 32768 + grp * 16384;

  // prologue: stage tile 0 into buffer 0
#pragma unroll
  for (int j = 0; j < 2; ++j) {
    const int c = j * 256 + wq * 64 + lane;
    gll16(Kg + (size_t)c * 8, Kbuf + j * 4096 + wq * 1024);
    gll16(Vg + (size_t)c * 8, Vbuf + j * 4096 + wq * 1024);
  }

  for (int t = 0; t < 32; ++t) {
    const int cur = t & 1;
    asm volatile("s_waitcnt vmcnt(0)" ::: "memory");
    __syncthreads();
    if (t + 1 < 32) {  // issue next tile; flies during this tile's compute
      const unsigned short* Kn = Kg + (size_t)(t + 1) * 4096;
      const unsigned short* Vn = Vg + (size_t)(t + 1) * 4096;
      char* kd = Kbuf + (cur ^ 1) * 8192;
      char* vd = Vbuf + (cur ^ 1) * 8192;
#pragma unroll
      for (int j = 0; j < 2; ++j) {
        const int c = j * 256 + wq * 64 + lane;
        gll16(Kn + (size_t)c * 8, kd + j * 4096 + wq * 1024);
        gll16(Vn + (size_t)c * 8, vd + j * 4096 + wq * 1024);
      }
    }

    const char* Kc = (const char*)Kbuf + cur * 8192;
    const char* Vc = (const char*)Vbuf + cur * 8192;

    // K fragments, shared by both m-blocks
    bf16x8 kf0[4], kf1[4];
#pragma unroll
    for (int kb = 0; kb < 4; ++kb) {
      kf0[kb] = *(const bf16x8*)(Kc + (kb * 128 + g * 32 + lr) * 16);
      kf1[kb] = *(const bf16x8*)(Kc + (kb * 128 + g * 32 + 16 + lr) * 16);
    }

    bf16x8 ap[2];
#pragma unroll
    for (int m = 0; m < 2; ++m) {
      f32x4 st0 = (f32x4){0.f, 0.f, 0.f, 0.f};
      f32x4 st1 = (f32x4){0.f, 0.f, 0.f, 0.f};
      __builtin_amdgcn_s_setprio(1);
#pragma unroll
      for (int kb = 0; kb < 4; ++kb) {
        st0 = mfma16(kf0[kb], qf[m][kb], st0);
        st1 = mfma16(kf1[kb], qf[m][kb], st1);
      }
      __builtin_amdgcn_s_setprio(0);
      float mt = fmaxf(fmaxf(fmaxf(st0[0], st0[1]), fmaxf(st0[2], st0[3])),
                       fmaxf(fmaxf(st1[0], st1[1]), fmaxf(st1[2], st1[3])));
      mt = fmaxf(mt, __shfl_xor(mt, 16));
      mt = fmaxf(mt, __shfl_xor(mt, 32));
      if (!__all(mt <= mrun[m] + 8.0f)) {  // rare rescale (defer-max)
        const float mnew = fmaxf(mrun[m], mt);
        const float corr = __builtin_amdgcn_exp2f(mrun[m] - mnew);
        lrun[m] *= corr;
        mrun[m] = mnew;
        const f32x4 cv = (f32x4){__shfl(corr, g * 4 + 0), __shfl(corr, g * 4 + 1),
                                 __shfl(corr, g * 4 + 2), __shfl(corr, g * 4 + 3)};
#pragma unroll
        for (int dn = 0; dn < 8; ++dn) acc[m][dn] *= cv;
      }
      float p[8], ls = 0.f;
#pragma unroll
      for (int r = 0; r < 4; ++r) {
        p[r] = __builtin_amdgcn_exp2f(st0[r] - mrun[m]);
        p[4 + r] = __builtin_amdgcn_exp2f(st1[r] - mrun[m]);
        ls += p[r] + p[4 + r];
      }
      lrun[m] += ls;  // per-lane partial; cross-lane reduce deferred to end
      uint2 pk0, pk1;
      pk0.x = cvtpk(p[0], p[1]); pk0.y = cvtpk(p[2], p[3]);
      pk1.x = cvtpk(p[4], p[5]); pk1.y = cvtpk(p[6], p[7]);
      *(uint2*)&Pwme[lr * 40 + 4 * g] = pk0;
      *(uint2*)&Pwme[lr * 40 + 16 + 4 * g] = pk1;
      ap[m] = *(const bf16x8*)&Pwme[lr * 40 + 8 * g];
    }
    // PV
    __builtin_amdgcn_s_setprio(1);
#pragma unroll
    for (int dn = 0; dn < 8; ++dn) {
      bf16x8 vf = *(const bf16x8*)(Vc + (g * 128 + dn * 16 + lr) * 16);
      acc[0][dn] = mfma16(ap[0], vf, acc[0][dn]);
      acc[1][dn] = mfma16(ap[1], vf, acc[1][dn]);
    }
    __builtin_amdgcn_s_setprio(0);
  }

  // finalize per-lane lrun -> full row sums
#pragma unroll
  for (int m = 0; m < 2; ++m) {
    lrun[m] += __shfl_xor(lrun[m], 16);
    lrun[m] += __shfl_xor(lrun[m], 32);
  }

  __syncthreads();  // all staging reads done; SM[0,65536) reusable
  float* ACCB = (float*)SM;                     // [ (wq*2+m)*8+dn ][lane] f32x4
  float2* MLB = (float2*)(SM + 75776);          // [wq*32 + m*16 + lr]
  if (grp == 1) {
#pragma unroll
    for (int m = 0; m < 2; ++m) {
#pragma unroll
      for (int dn = 0; dn < 8; ++dn)
        *(f32x4*)(ACCB + ((size_t)((wq * 2 + m) * 8 + dn)) * 256 + lane * 4) =
            acc[m][dn];
      if (lane < 16) MLB[wq * 32 + m * 16 + lr] = make_float2(mrun[m], lrun[m]);
    }
  }
  __syncthreads();

  if (grp == 0) {
    const int b = bh >> 4, h = bh & 15;
#pragma unroll
    for (int m = 0; m < 2; ++m) {
      const float2 ml1 = MLB[wq * 32 + m * 16 + lr];
      const float mstar = fmaxf(mrun[m], ml1.x);
      const float c0 = __builtin_amdgcn_exp2f(mrun[m] - mstar);
      const float c1 = __builtin_amdgcn_exp2f(ml1.x - mstar);
      const float inv = 1.f / (lrun[m] * c0 + ml1.y * c1);
      const float a0 = c0 * inv, a1 = c1 * inv;
      f32x4 a0v, a1v;
#pragma unroll
      for (int r = 0; r < 4; ++r) {
        a0v[r] = __shfl(a0, g * 4 + r);
        a1v[r] = __shfl(a1, g * 4 + r);
      }
#pragma unroll
      for (int dn = 0; dn < 8; ++dn) {
        const f32x4 pacc =
            *(const f32x4*)(ACCB + ((size_t)((wq * 2 + m) * 8 + dn)) * 256 + lane * 4);
        const f32x4 o = acc[m][dn] * a0v + pacc * a1v;
#pragma unroll
        for (int r = 0; r < 4; ++r) {
          const int srow = q0 + wq * 32 + m * 16 + g * 4 + r;
          Ab[((size_t)(b * SEQ + srow) * NHEADS + h) * DH + dn * 16 + lr] = f2bf(o[r]);
        }
      }
    }
  }
}

// ---------------------------------------------------------------------------
extern "C" void kernel_launch(void* const* d_in, const int* in_sizes, int n_in,
                              void* d_out, int out_size, void* d_ws,
                              size_t ws_size, hipStream_t stream) {
  const float* X  = (const float*)d_in[0];
  const float* Wq = (const float*)d_in[1];
  const float* Wk = (const float*)d_in[2];
  const float* Wv = (const float*)d_in[3];
  const float* Wo = (const float*)d_in[4];
  float* out = (float*)d_out;

  const int n1 = MTOT * HIDDEN;    // 8388608
  const int n2 = HIDDEN * HIDDEN;  // 4194304

  char* p = (char*)d_ws;
  unsigned short* Xb  = (unsigned short*)(p + 0);          // 16 MB
  unsigned short* Wqb = (unsigned short*)(p + 16777216);   // 8 MB
  unsigned short* Wkb = (unsigned short*)(p + 25165824);   // 8 MB
  unsigned short* Wvb = (unsigned short*)(p + 33554432);   // 8 MB
  unsigned short* Woh = (unsigned short*)(p + 41943040);   // 8 MB
  unsigned short* Wol = (unsigned short*)(p + 50331648);   // 8 MB
  unsigned short* Qb  = (unsigned short*)(p + 58720256);   // 16 MB
  unsigned short* Kb  = (unsigned short*)(p + 75497472);   // 16 MB
  unsigned short* Vb  = (unsigned short*)(p + 92274688);   // 16 MB
  unsigned short* Ab  = (unsigned short*)(p + 109051904);  // 16 MB (ends 125829120)

  cast_bf16_kernel<<<n1 / 1024, 256, 0, stream>>>(X, Xb, n1);
  cast_bf16_kernel<<<n2 / 1024, 256, 0, stream>>>(Wq, Wqb, n2);
  cast_bf16_kernel<<<n2 / 1024, 256, 0, stream>>>(Wk, Wkb, n2);
  cast_bf16_kernel<<<n2 / 1024, 256, 0, stream>>>(Wv, Wvb, n2);
  cast_split_kernel<<<n2 / 1024, 256, 0, stream>>>(Wo, Woh, Wol, n2);

  const dim3 ggrid(HIDDEN / 128, MTOT / 128);  // (16, 32)
  gemm_qkv<0><<<ggrid, 256, 0, stream>>>(Xb, Wqb, Qb, QSCALE);
  gemm_qkv<1><<<ggrid, 256, 0, stream>>>(Xb, Wkb, Kb, 1.0f);
  gemm_qkv<2><<<ggrid, 256, 0, stream>>>(Xb, Wvb, Vb, 1.0f);

  attn_mfma<<<dim3(512), 512, 0, stream>>>(Qb, Kb, Vb, Ab);

  gemm_osplit<<<ggrid, 256, 0, stream>>>(Ab, Woh, Wol, out);
}

// Round 5
// 389.950 us; speedup vs baseline: 1.2845x; 1.2845x over previous
//
#include <hip/hip_runtime.h>
#include <cstdint>

#define HIDDEN 2048
#define NHEADS 16
#define DH 128
#define BATCH 2
#define SEQ 2048
#define MTOT 4096
#define BH (BATCH * NHEADS)

typedef __attribute__((ext_vector_type(8))) short bf16x8;
typedef __attribute__((ext_vector_type(4))) float f32x4;

// SCALE * log2(e): scores come out of QK^T already in log2 domain
static constexpr float QSCALE = (float)(0.08838834764831845 * 1.4426950408889634);

__device__ __forceinline__ unsigned short f2bf(float f) {
  union { float f; uint32_t u; } v; v.f = f;
  uint32_t r = v.u + 0x7FFFu + ((v.u >> 16) & 1u);
  return (unsigned short)(r >> 16);
}
__device__ __forceinline__ float bf2f(unsigned short h) {
  union { uint32_t u; float f; } v; v.u = ((uint32_t)h) << 16;
  return v.f;
}
__device__ __forceinline__ uint32_t cvtpk(float lo, float hi) {
  uint32_t r;
  asm("v_cvt_pk_bf16_f32 %0, %1, %2" : "=v"(r) : "v"(lo), "v"(hi));
  return r;
}
__device__ __forceinline__ f32x4 mfma16(bf16x8 a, bf16x8 b, f32x4 c) {
  return __builtin_amdgcn_mfma_f32_16x16x32_bf16(a, b, c, 0, 0, 0);
}

typedef const __attribute__((address_space(1))) unsigned char* gas1_t;
typedef __attribute__((address_space(3))) unsigned char* las3_t;
__device__ __forceinline__ void gll16(const void* g, void* l) {
  __builtin_amdgcn_global_load_lds((gas1_t)g, (las3_t)l, 16, 0, 0);
}

// ---------------------------------------------------------------------------
// casts
// ---------------------------------------------------------------------------
__global__ __launch_bounds__(256) void cast_bf16_kernel(const float* __restrict__ in,
                                                        unsigned short* __restrict__ out,
                                                        int n) {
  int i = (blockIdx.x * 256 + threadIdx.x) * 4;
  if (i < n) {
    float4 f = *(const float4*)&in[i];
    ushort4 o;
    o.x = f2bf(f.x); o.y = f2bf(f.y); o.z = f2bf(f.z); o.w = f2bf(f.w);
    *(ushort4*)&out[i] = o;
  }
}

__global__ __launch_bounds__(256) void cast_split_kernel(const float* __restrict__ in,
                                                         unsigned short* __restrict__ hi,
                                                         unsigned short* __restrict__ lo,
                                                         int n) {
  int i = (blockIdx.x * 256 + threadIdx.x) * 4;
  if (i < n) {
    float4 f = *(const float4*)&in[i];
    ushort4 h, l;
    h.x = f2bf(f.x); l.x = f2bf(f.x - bf2f(h.x));
    h.y = f2bf(f.y); l.y = f2bf(f.y - bf2f(h.y));
    h.z = f2bf(f.z); l.z = f2bf(f.z - bf2f(h.z));
    h.w = f2bf(f.w); l.w = f2bf(f.w - bf2f(h.w));
    *(ushort4*)&hi[i] = h;
    *(ushort4*)&lo[i] = l;
  }
}

// ---------------------------------------------------------------------------
// Fused Q/K/V projection GEMM (m97 structure, global_load_lds staging).
// grid.x in [0,48): which = x>>4 selects {Q,K,V}, n0 = (x&15)*128.
// which 0: Q [BH][S][D] (alpha=QSCALE); 1: K blocked [BH][S/32][d/8][s%32][8];
// 2: V blocked [BH][S/8][D][8].
// ---------------------------------------------------------------------------
__global__ __launch_bounds__(256) void gemm_qkv3(const unsigned short* __restrict__ A,
                                                 const unsigned short* __restrict__ Wq,
                                                 const unsigned short* __restrict__ Wk,
                                                 const unsigned short* __restrict__ Wv,
                                                 unsigned short* __restrict__ Qb,
                                                 unsigned short* __restrict__ Kb,
                                                 unsigned short* __restrict__ Vb) {
  __shared__ __align__(16) unsigned short As[4096];
  __shared__ __align__(16) unsigned short Ws[4096];
  const int tid = threadIdx.x;
  const int lane = tid & 63, wv = tid >> 6;
  const int wr = wv >> 1, wc = wv & 1;
  const int g = lane >> 4, lr = lane & 15;
  const int which = blockIdx.x >> 4;
  const int m0 = blockIdx.y * 128, n0 = (blockIdx.x & 15) * 128;
  const unsigned short* W = (which == 0) ? Wq : (which == 1) ? Wk : Wv;
  const float alpha = (which == 0) ? QSCALE : 1.0f;

  f32x4 acc[4][4];
#pragma unroll
  for (int i = 0; i < 4; ++i)
#pragma unroll
    for (int j = 0; j < 4; ++j) acc[i][j] = (f32x4){0.f, 0.f, 0.f, 0.f};

  const int c0 = tid, c1 = 256 + tid;
  const int row0 = c0 >> 2, kb0 = (c0 & 3) ^ ((row0 >> 1) & 3);
  const int row1 = c1 >> 2, kb1 = (c1 & 3) ^ ((row1 >> 1) & 3);
  const size_t aoff0 = (size_t)(m0 + row0) * HIDDEN + kb0 * 8;
  const size_t aoff1 = (size_t)(m0 + row1) * HIDDEN + kb1 * 8;
  const size_t woff0 = (size_t)(n0 + row0) * HIDDEN + kb0 * 8;
  const size_t woff1 = (size_t)(n0 + row1) * HIDDEN + kb1 * 8;
  const int swz = ((lr >> 1) & 3) * 16;

  for (int k0 = 0; k0 < HIDDEN; k0 += 32) {
    __syncthreads();
    gll16(A + aoff0 + k0, (char*)As + wv * 1024);
    gll16(W + woff0 + k0, (char*)Ws + wv * 1024);
    gll16(A + aoff1 + k0, (char*)As + 4096 + wv * 1024);
    gll16(W + woff1 + k0, (char*)Ws + 4096 + wv * 1024);
    __syncthreads();

    bf16x8 af[4], wf[4];
#pragma unroll
    for (int mi = 0; mi < 4; ++mi) {
      const int row = wr * 64 + mi * 16 + lr;
      af[mi] = *(const bf16x8*)((const char*)As + row * 64 + ((g * 16) ^ swz));
    }
#pragma unroll
    for (int ni = 0; ni < 4; ++ni) {
      const int row = wc * 64 + ni * 16 + lr;
      wf[ni] = *(const bf16x8*)((const char*)Ws + row * 64 + ((g * 16) ^ swz));
    }
#pragma unroll
    for (int mi = 0; mi < 4; ++mi)
#pragma unroll
      for (int ni = 0; ni < 4; ++ni)
        acc[mi][ni] = mfma16(af[mi], wf[ni], acc[mi][ni]);
  }

  unsigned short* C = (which == 0) ? Qb : (which == 1) ? Kb : Vb;
#pragma unroll
  for (int mi = 0; mi < 4; ++mi)
#pragma unroll
    for (int ni = 0; ni < 4; ++ni)
#pragma unroll
      for (int r = 0; r < 4; ++r) {
        const int row = m0 + wr * 64 + mi * 16 + g * 4 + r;
        const int col = n0 + wc * 64 + ni * 16 + lr;
        const unsigned short v = f2bf(acc[mi][ni][r] * alpha);
        const int b = row >> 11, s = row & (SEQ - 1);
        const int h = col >> 7, d = col & (DH - 1);
        const size_t base = (size_t)(b * NHEADS + h) * SEQ * DH;
        if (which == 0)
          C[base + (size_t)s * DH + d] = v;
        else if (which == 1)
          C[base + (size_t)(s >> 5) * 4096 + (d >> 3) * 256 + (s & 31) * 8 + (d & 7)] = v;
        else
          C[base + (size_t)(s >> 3) * 1024 + d * 8 + (s & 7)] = v;
      }
}

// ---------------------------------------------------------------------------
// Split-bf16x2 O-proj (unchanged)
// ---------------------------------------------------------------------------
__global__ __launch_bounds__(256) void gemm_osplit(const unsigned short* __restrict__ A,
                                                   const unsigned short* __restrict__ Wh,
                                                   const unsigned short* __restrict__ Wl,
                                                   float* __restrict__ C) {
  __shared__ __align__(16) unsigned short As[4096];
  __shared__ __align__(16) unsigned short Whs[4096];
  __shared__ __align__(16) unsigned short Wls[4096];
  const int tid = threadIdx.x;
  const int lane = tid & 63, wv = tid >> 6;
  const int wr = wv >> 1, wc = wv & 1;
  const int g = lane >> 4, lr = lane & 15;
  const int m0 = blockIdx.y * 128, n0 = blockIdx.x * 128;

  f32x4 acc[4][4];
#pragma unroll
  for (int i = 0; i < 4; ++i)
#pragma unroll
    for (int j = 0; j < 4; ++j) acc[i][j] = (f32x4){0.f, 0.f, 0.f, 0.f};

  const int c0 = tid, c1 = 256 + tid;
  const int row0 = c0 >> 2, kb0 = (c0 & 3) ^ ((row0 >> 1) & 3);
  const int row1 = c1 >> 2, kb1 = (c1 & 3) ^ ((row1 >> 1) & 3);
  const size_t aoff0 = (size_t)(m0 + row0) * HIDDEN + kb0 * 8;
  const size_t aoff1 = (size_t)(m0 + row1) * HIDDEN + kb1 * 8;
  const size_t woff0 = (size_t)(n0 + row0) * HIDDEN + kb0 * 8;
  const size_t woff1 = (size_t)(n0 + row1) * HIDDEN + kb1 * 8;
  const int swz = ((lr >> 1) & 3) * 16;

  for (int k0 = 0; k0 < HIDDEN; k0 += 32) {
    __syncthreads();
    gll16(A + aoff0 + k0, (char*)As + wv * 1024);
    gll16(Wh + woff0 + k0, (char*)Whs + wv * 1024);
    gll16(Wl + woff0 + k0, (char*)Wls + wv * 1024);
    gll16(A + aoff1 + k0, (char*)As + 4096 + wv * 1024);
    gll16(Wh + woff1 + k0, (char*)Whs + 4096 + wv * 1024);
    gll16(Wl + woff1 + k0, (char*)Wls + 4096 + wv * 1024);
    __syncthreads();

    bf16x8 af[4], wfh[4], wfl[4];
#pragma unroll
    for (int mi = 0; mi < 4; ++mi) {
      const int row = wr * 64 + mi * 16 + lr;
      af[mi] = *(const bf16x8*)((const char*)As + row * 64 + ((g * 16) ^ swz));
    }
#pragma unroll
    for (int ni = 0; ni < 4; ++ni) {
      const int row = wc * 64 + ni * 16 + lr;
      wfh[ni] = *(const bf16x8*)((const char*)Whs + row * 64 + ((g * 16) ^ swz));
      wfl[ni] = *(const bf16x8*)((const char*)Wls + row * 64 + ((g * 16) ^ swz));
    }
#pragma unroll
    for (int mi = 0; mi < 4; ++mi)
#pragma unroll
      for (int ni = 0; ni < 4; ++ni) {
        acc[mi][ni] = mfma16(af[mi], wfh[ni], acc[mi][ni]);
        acc[mi][ni] = mfma16(af[mi], wfl[ni], acc[mi][ni]);
      }
  }

#pragma unroll
  for (int mi = 0; mi < 4; ++mi)
#pragma unroll
    for (int ni = 0; ni < 4; ++ni)
#pragma unroll
      for (int r = 0; r < 4; ++r) {
        const int row = m0 + wr * 64 + mi * 16 + g * 4 + r;
        const int col = n0 + wc * 64 + ni * 16 + lr;
        C[(size_t)row * HIDDEN + col] = acc[mi][ni][r];
      }
}

// ---------------------------------------------------------------------------
// MFMA flash attention, KV-split across blocks: blockIdx.z = part in {0,1},
// each block handles keys [part*1024, part*1024+1024) for its 128 q-rows.
// Block = 256 thr / 4 waves (r3 resource profile: VGPR ~84, LDS 37888 ->
// 4 blocks/CU = 16 waves/CU). Writes UNNORMALIZED partial O (bf16) + (m,l).
// Log2-domain softmax, defer-max, per-lane deferred l-sum.
// ---------------------------------------------------------------------------
__global__ __launch_bounds__(256, 4) void attn_mfma(const unsigned short* __restrict__ Q,
                                                    const unsigned short* __restrict__ K,
                                                    const unsigned short* __restrict__ V,
                                                    unsigned short* __restrict__ Pb,
                                                    float2* __restrict__ ML) {
  const int bh = blockIdx.y;
  const int q0 = blockIdx.x * 128;
  const int part = blockIdx.z;
  const int tid = threadIdx.x;
  const int wv = tid >> 6, lane = tid & 63;
  const int g = lane >> 4, lr = lane & 15;
  const unsigned short* Qh = Q + (size_t)bh * SEQ * DH;
  const unsigned short* Kh = K + (size_t)bh * SEQ * DH + (size_t)part * (SEQ / 2) * DH;
  const unsigned short* Vh = V + (size_t)bh * SEQ * DH + (size_t)part * (SEQ / 2) * DH;

  __shared__ __align__(16) unsigned short Kls[2][4096];
  __shared__ __align__(16) unsigned short Vls[2][4096];
  __shared__ __align__(16) unsigned short Pw[4][16][40];

  bf16x8 qf[2][4];
#pragma unroll
  for (int m = 0; m < 2; ++m)
#pragma unroll
    for (int kb = 0; kb < 4; ++kb)
      qf[m][kb] = *(const bf16x8*)&Qh[(size_t)(q0 + wv * 32 + m * 16 + lr) * DH +
                                      kb * 32 + g * 8];

  f32x4 acc[2][8];
#pragma unroll
  for (int m = 0; m < 2; ++m)
#pragma unroll
    for (int dn = 0; dn < 8; ++dn) acc[m][dn] = (f32x4){0.f, 0.f, 0.f, 0.f};
  float mrun[2] = {-1e30f, -1e30f};
  float lrun[2] = {0.f, 0.f};

  // prologue: stage tile 0 into buffer 0
#pragma unroll
  for (int j = 0; j < 2; ++j) {
    const int c = j * 256 + tid;
    gll16(Kh + (size_t)c * 8, (char*)&Kls[0][0] + j * 4096 + wv * 1024);
    gll16(Vh + (size_t)c * 8, (char*)&Vls[0][0] + j * 4096 + wv * 1024);
  }

  for (int t = 0; t < 32; ++t) {
    const int cur = t & 1;
    asm volatile("s_waitcnt vmcnt(0)" ::: "memory");
    __syncthreads();
    if (t + 1 < 32) {  // issue next tile; flies during this tile's compute
      const unsigned short* Kn = Kh + (size_t)(t + 1) * 4096;
      const unsigned short* Vn = Vh + (size_t)(t + 1) * 4096;
      char* kd = (char*)&Kls[cur ^ 1][0];
      char* vd = (char*)&Vls[cur ^ 1][0];
#pragma unroll
      for (int j = 0; j < 2; ++j) {
        const int c = j * 256 + tid;
        gll16(Kn + (size_t)c * 8, kd + j * 4096 + wv * 1024);
        gll16(Vn + (size_t)c * 8, vd + j * 4096 + wv * 1024);
      }
    }

    const char* Kc = (const char*)&Kls[cur][0];
    const char* Vc = (const char*)&Vls[cur][0];
    bf16x8 ap[2];
#pragma unroll
    for (int m = 0; m < 2; ++m) {
      f32x4 st0 = (f32x4){0.f, 0.f, 0.f, 0.f};
      f32x4 st1 = (f32x4){0.f, 0.f, 0.f, 0.f};
      __builtin_amdgcn_s_setprio(1);
#pragma unroll
      for (int kb = 0; kb < 4; ++kb) {
        const int cb = (kb * 4 + g) * 32;
        bf16x8 kf0 = *(const bf16x8*)(Kc + (cb + lr) * 16);
        bf16x8 kf1 = *(const bf16x8*)(Kc + (cb + 16 + lr) * 16);
        st0 = mfma16(kf0, qf[m][kb], st0);
        st1 = mfma16(kf1, qf[m][kb], st1);
      }
      __builtin_amdgcn_s_setprio(0);
      float mt = fmaxf(fmaxf(fmaxf(st0[0], st0[1]), fmaxf(st0[2], st0[3])),
                       fmaxf(fmaxf(st1[0], st1[1]), fmaxf(st1[2], st1[3])));
      mt = fmaxf(mt, __shfl_xor(mt, 16));
      mt = fmaxf(mt, __shfl_xor(mt, 32));
      if (!__all(mt <= mrun[m] + 8.0f)) {  // rare rescale (defer-max)
        const float mnew = fmaxf(mrun[m], mt);
        const float corr = __builtin_amdgcn_exp2f(mrun[m] - mnew);
        lrun[m] *= corr;
        mrun[m] = mnew;
        const f32x4 cv = (f32x4){__shfl(corr, g * 4 + 0), __shfl(corr, g * 4 + 1),
                                 __shfl(corr, g * 4 + 2), __shfl(corr, g * 4 + 3)};
#pragma unroll
        for (int dn = 0; dn < 8; ++dn) acc[m][dn] *= cv;
      }
      float p[8], ls = 0.f;
#pragma unroll
      for (int r = 0; r < 4; ++r) {
        p[r] = __builtin_amdgcn_exp2f(st0[r] - mrun[m]);
        p[4 + r] = __builtin_amdgcn_exp2f(st1[r] - mrun[m]);
        ls += p[r] + p[4 + r];
      }
      lrun[m] += ls;  // per-lane partial; cross-lane reduce deferred to end
      uint2 pk0, pk1;
      pk0.x = cvtpk(p[0], p[1]); pk0.y = cvtpk(p[2], p[3]);
      pk1.x = cvtpk(p[4], p[5]); pk1.y = cvtpk(p[6], p[7]);
      *(uint2*)&Pw[wv][lr][4 * g] = pk0;
      *(uint2*)&Pw[wv][lr][16 + 4 * g] = pk1;
      ap[m] = *(const bf16x8*)&Pw[wv][lr][8 * g];
    }
    // PV
    __builtin_amdgcn_s_setprio(1);
#pragma unroll
    for (int dn = 0; dn < 8; ++dn) {
      bf16x8 vf = *(const bf16x8*)(Vc + (g * 128 + dn * 16 + lr) * 16);
      acc[0][dn] = mfma16(ap[0], vf, acc[0][dn]);
      acc[1][dn] = mfma16(ap[1], vf, acc[1][dn]);
    }
    __builtin_amdgcn_s_setprio(0);
  }

  const int b = bh >> 4, h = bh & 15;
  unsigned short* Pp = Pb + (size_t)part * MTOT * HIDDEN;
#pragma unroll
  for (int m = 0; m < 2; ++m) {
    // finalize per-lane l -> full row sum (q-row = lr)
    lrun[m] += __shfl_xor(lrun[m], 16);
    lrun[m] += __shfl_xor(lrun[m], 32);
    if (lane < 16) {
      const int mlrow = q0 + wv * 32 + m * 16 + lr;
      ML[(size_t)part * (MTOT * NHEADS) + (size_t)(b * SEQ + mlrow) * NHEADS + h] =
          make_float2(mrun[m], lrun[m]);
    }
#pragma unroll
    for (int dn = 0; dn < 8; ++dn)
#pragma unroll
      for (int r = 0; r < 4; ++r) {
        const int srow = q0 + wv * 32 + m * 16 + g * 4 + r;
        Pp[((size_t)(b * SEQ + srow) * NHEADS + h) * DH + dn * 16 + lr] =
            f2bf(acc[m][dn][r]);
      }
  }
}

// ---------------------------------------------------------------------------
// Combine the two KV-split partials: O = (c0*A0 + c1*A1) / (c0*l0 + c1*l1),
// c_p = exp2(m_p - max(m0,m1)). One thread per 8 dims.
// ---------------------------------------------------------------------------
__global__ __launch_bounds__(256) void attn_combine(const unsigned short* __restrict__ Pb,
                                                    const float2* __restrict__ ML,
                                                    unsigned short* __restrict__ Ab) {
  const int idx = blockIdx.x * 256 + threadIdx.x;  // MTOT*NHEADS*16 total
  const int row = idx >> 4;
  const int dj = (idx & 15) * 8;
  const float2 ml0 = ML[row];
  const float2 ml1 = ML[MTOT * NHEADS + row];
  const float ms = fmaxf(ml0.x, ml1.x);
  const float c0 = __builtin_amdgcn_exp2f(ml0.x - ms);
  const float c1 = __builtin_amdgcn_exp2f(ml1.x - ms);
  const float inv = 1.f / (c0 * ml0.y + c1 * ml1.y);
  const float w0 = c0 * inv, w1 = c1 * inv;
  const size_t off = (size_t)row * DH + dj;
  const bf16x8 a0 = *(const bf16x8*)&Pb[off];
  const bf16x8 a1 = *(const bf16x8*)&Pb[(size_t)MTOT * HIDDEN + off];
  unsigned short o[8];
#pragma unroll
  for (int j = 0; j < 8; ++j)
    o[j] = f2bf(bf2f((unsigned short)a0[j]) * w0 + bf2f((unsigned short)a1[j]) * w1);
  *(bf16x8*)&Ab[off] = *(const bf16x8*)o;
}

// ---------------------------------------------------------------------------
extern "C" void kernel_launch(void* const* d_in, const int* in_sizes, int n_in,
                              void* d_out, int out_size, void* d_ws,
                              size_t ws_size, hipStream_t stream) {
  const float* X  = (const float*)d_in[0];
  const float* Wq = (const float*)d_in[1];
  const float* Wk = (const float*)d_in[2];
  const float* Wv = (const float*)d_in[3];
  const float* Wo = (const float*)d_in[4];
  float* out = (float*)d_out;

  const int n1 = MTOT * HIDDEN;    // 8388608
  const int n2 = HIDDEN * HIDDEN;  // 4194304

  char* p = (char*)d_ws;
  unsigned short* Xb  = (unsigned short*)(p + 0);          // 16 MB (dead after qkv3)
  unsigned short* Qb  = (unsigned short*)(p + 16777216);   // 16 MB
  unsigned short* Kb  = (unsigned short*)(p + 33554432);   // 16 MB
  unsigned short* Vb  = (unsigned short*)(p + 50331648);   // 16 MB
  unsigned short* Woh = (unsigned short*)(p + 67108864);   // 8 MB
  unsigned short* Wol = (unsigned short*)(p + 75497472);   // 8 MB
  unsigned short* Wqb = (unsigned short*)(p + 83886080);   // 8 MB (dead after qkv3)
  unsigned short* Wkb = (unsigned short*)(p + 92274688);   // 8 MB (dead after qkv3)
  unsigned short* Wvb = (unsigned short*)(p + 100663296);  // 8 MB (dead after qkv3)
  unsigned short* Pb  = (unsigned short*)(p + 83886080);   // 32 MB partials (alias W*b)
  float2*         ML  = (float2*)(p + 117440512);          // 1 MB (ends 118489088)
  unsigned short* Ab  = (unsigned short*)(p + 0);          // 16 MB (alias dead Xb)

  cast_bf16_kernel<<<n1 / 1024, 256, 0, stream>>>(X, Xb, n1);
  cast_bf16_kernel<<<n2 / 1024, 256, 0, stream>>>(Wq, Wqb, n2);
  cast_bf16_kernel<<<n2 / 1024, 256, 0, stream>>>(Wk, Wkb, n2);
  cast_bf16_kernel<<<n2 / 1024, 256, 0, stream>>>(Wv, Wvb, n2);
  cast_split_kernel<<<n2 / 1024, 256, 0, stream>>>(Wo, Woh, Wol, n2);

  gemm_qkv3<<<dim3(48, MTOT / 128), 256, 0, stream>>>(Xb, Wqb, Wkb, Wvb, Qb, Kb, Vb);

  attn_mfma<<<dim3(SEQ / 128, BH, 2), 256, 0, stream>>>(Qb, Kb, Vb, Pb, ML);

  attn_combine<<<(MTOT * NHEADS * 16) / 256, 256, 0, stream>>>(Pb, ML, Ab);

  gemm_osplit<<<dim3(HIDDEN / 128, MTOT / 128), 256, 0, stream>>>(Ab, Woh, Wol, out);
}

// Round 6
// 304.821 us; speedup vs baseline: 1.6432x; 1.2793x over previous
//
#include <hip/hip_runtime.h>
#include <cstdint>

#define HIDDEN 2048
#define NHEADS 16
#define DH 128
#define BATCH 2
#define SEQ 2048
#define MTOT 4096
#define BH (BATCH * NHEADS)

typedef __attribute__((ext_vector_type(8))) short bf16x8;
typedef __attribute__((ext_vector_type(4))) float f32x4;

// SCALE * log2(e): scores come out of QK^T already in log2 domain
static constexpr float QSCALE = (float)(0.08838834764831845 * 1.4426950408889634);

__device__ __forceinline__ unsigned short f2bf(float f) {
  union { float f; uint32_t u; } v; v.f = f;
  uint32_t r = v.u + 0x7FFFu + ((v.u >> 16) & 1u);
  return (unsigned short)(r >> 16);
}
__device__ __forceinline__ uint32_t cvtpk(float lo, float hi) {
  uint32_t r;
  asm("v_cvt_pk_bf16_f32 %0, %1, %2" : "=v"(r) : "v"(lo), "v"(hi));
  return r;
}
__device__ __forceinline__ f32x4 mfma16(bf16x8 a, bf16x8 b, f32x4 c) {
  return __builtin_amdgcn_mfma_f32_16x16x32_bf16(a, b, c, 0, 0, 0);
}

typedef const __attribute__((address_space(1))) unsigned char* gas1_t;
typedef __attribute__((address_space(3))) unsigned char* las3_t;
__device__ __forceinline__ void gll16(const void* g, void* l) {
  __builtin_amdgcn_global_load_lds((gas1_t)g, (las3_t)l, 16, 0, 0);
}

// ---------------------------------------------------------------------------
// cast fp32 -> bf16
// ---------------------------------------------------------------------------
__global__ __launch_bounds__(256) void cast_bf16_kernel(const float* __restrict__ in,
                                                        unsigned short* __restrict__ out,
                                                        int n) {
  int i = (blockIdx.x * 256 + threadIdx.x) * 4;
  if (i < n) {
    float4 f = *(const float4*)&in[i];
    ushort4 o;
    o.x = f2bf(f.x); o.y = f2bf(f.y); o.z = f2bf(f.z); o.w = f2bf(f.w);
    *(ushort4*)&out[i] = o;
  }
}

// ---------------------------------------------------------------------------
// Fused Q/K/V projection GEMM (m97 structure, global_load_lds staging).
// grid.x in [0,48): which = x>>4 selects {Q,K,V}, n0 = (x&15)*128.
// which 0: Q [BH][S][D] (alpha=QSCALE); 1: K blocked [BH][S/32][d/8][s%32][8];
// 2: V blocked [BH][S/8][D][8].
// ---------------------------------------------------------------------------
__global__ __launch_bounds__(256) void gemm_qkv3(const unsigned short* __restrict__ A,
                                                 const unsigned short* __restrict__ Wq,
                                                 const unsigned short* __restrict__ Wk,
                                                 const unsigned short* __restrict__ Wv,
                                                 unsigned short* __restrict__ Qb,
                                                 unsigned short* __restrict__ Kb,
                                                 unsigned short* __restrict__ Vb) {
  __shared__ __align__(16) unsigned short As[4096];
  __shared__ __align__(16) unsigned short Ws[4096];
  const int tid = threadIdx.x;
  const int lane = tid & 63, wv = tid >> 6;
  const int wr = wv >> 1, wc = wv & 1;
  const int g = lane >> 4, lr = lane & 15;
  const int which = blockIdx.x >> 4;
  const int m0 = blockIdx.y * 128, n0 = (blockIdx.x & 15) * 128;
  const unsigned short* W = (which == 0) ? Wq : (which == 1) ? Wk : Wv;
  const float alpha = (which == 0) ? QSCALE : 1.0f;

  f32x4 acc[4][4];
#pragma unroll
  for (int i = 0; i < 4; ++i)
#pragma unroll
    for (int j = 0; j < 4; ++j) acc[i][j] = (f32x4){0.f, 0.f, 0.f, 0.f};

  const int c0 = tid, c1 = 256 + tid;
  const int row0 = c0 >> 2, kb0 = (c0 & 3) ^ ((row0 >> 1) & 3);
  const int row1 = c1 >> 2, kb1 = (c1 & 3) ^ ((row1 >> 1) & 3);
  const size_t aoff0 = (size_t)(m0 + row0) * HIDDEN + kb0 * 8;
  const size_t aoff1 = (size_t)(m0 + row1) * HIDDEN + kb1 * 8;
  const size_t woff0 = (size_t)(n0 + row0) * HIDDEN + kb0 * 8;
  const size_t woff1 = (size_t)(n0 + row1) * HIDDEN + kb1 * 8;
  const int swz = ((lr >> 1) & 3) * 16;

  for (int k0 = 0; k0 < HIDDEN; k0 += 32) {
    __syncthreads();
    gll16(A + aoff0 + k0, (char*)As + wv * 1024);
    gll16(W + woff0 + k0, (char*)Ws + wv * 1024);
    gll16(A + aoff1 + k0, (char*)As + 4096 + wv * 1024);
    gll16(W + woff1 + k0, (char*)Ws + 4096 + wv * 1024);
    __syncthreads();

    bf16x8 af[4], wf[4];
#pragma unroll
    for (int mi = 0; mi < 4; ++mi) {
      const int row = wr * 64 + mi * 16 + lr;
      af[mi] = *(const bf16x8*)((const char*)As + row * 64 + ((g * 16) ^ swz));
    }
#pragma unroll
    for (int ni = 0; ni < 4; ++ni) {
      const int row = wc * 64 + ni * 16 + lr;
      wf[ni] = *(const bf16x8*)((const char*)Ws + row * 64 + ((g * 16) ^ swz));
    }
#pragma unroll
    for (int mi = 0; mi < 4; ++mi)
#pragma unroll
      for (int ni = 0; ni < 4; ++ni)
        acc[mi][ni] = mfma16(af[mi], wf[ni], acc[mi][ni]);
  }

  unsigned short* C = (which == 0) ? Qb : (which == 1) ? Kb : Vb;
#pragma unroll
  for (int mi = 0; mi < 4; ++mi)
#pragma unroll
    for (int ni = 0; ni < 4; ++ni)
#pragma unroll
      for (int r = 0; r < 4; ++r) {
        const int row = m0 + wr * 64 + mi * 16 + g * 4 + r;
        const int col = n0 + wc * 64 + ni * 16 + lr;
        const unsigned short v = f2bf(acc[mi][ni][r] * alpha);
        const int b = row >> 11, s = row & (SEQ - 1);
        const int h = col >> 7, d = col & (DH - 1);
        const size_t base = (size_t)(b * NHEADS + h) * SEQ * DH;
        if (which == 0)
          C[base + (size_t)s * DH + d] = v;
        else if (which == 1)
          C[base + (size_t)(s >> 5) * 4096 + (d >> 3) * 256 + (s & 31) * 8 + (d & 7)] = v;
        else
          C[base + (size_t)(s >> 3) * 1024 + d * 8 + (s & 7)] = v;
      }
}

// ---------------------------------------------------------------------------
// Plain bf16 O-projection: C(f32) = A_bf16[M,K] @ W_bf16[N,K]^T
// (attention outputs have std ~0.07 -> bf16 W rounding adds only ~1e-4 abs)
// ---------------------------------------------------------------------------
__global__ __launch_bounds__(256) void gemm_out(const unsigned short* __restrict__ A,
                                                const unsigned short* __restrict__ W,
                                                float* __restrict__ C) {
  __shared__ __align__(16) unsigned short As[4096];
  __shared__ __align__(16) unsigned short Ws[4096];
  const int tid = threadIdx.x;
  const int lane = tid & 63, wv = tid >> 6;
  const int wr = wv >> 1, wc = wv & 1;
  const int g = lane >> 4, lr = lane & 15;
  const int m0 = blockIdx.y * 128, n0 = blockIdx.x * 128;

  f32x4 acc[4][4];
#pragma unroll
  for (int i = 0; i < 4; ++i)
#pragma unroll
    for (int j = 0; j < 4; ++j) acc[i][j] = (f32x4){0.f, 0.f, 0.f, 0.f};

  const int c0 = tid, c1 = 256 + tid;
  const int row0 = c0 >> 2, kb0 = (c0 & 3) ^ ((row0 >> 1) & 3);
  const int row1 = c1 >> 2, kb1 = (c1 & 3) ^ ((row1 >> 1) & 3);
  const size_t aoff0 = (size_t)(m0 + row0) * HIDDEN + kb0 * 8;
  const size_t aoff1 = (size_t)(m0 + row1) * HIDDEN + kb1 * 8;
  const size_t woff0 = (size_t)(n0 + row0) * HIDDEN + kb0 * 8;
  const size_t woff1 = (size_t)(n0 + row1) * HIDDEN + kb1 * 8;
  const int swz = ((lr >> 1) & 3) * 16;

  for (int k0 = 0; k0 < HIDDEN; k0 += 32) {
    __syncthreads();
    gll16(A + aoff0 + k0, (char*)As + wv * 1024);
    gll16(W + woff0 + k0, (char*)Ws + wv * 1024);
    gll16(A + aoff1 + k0, (char*)As + 4096 + wv * 1024);
    gll16(W + woff1 + k0, (char*)Ws + 4096 + wv * 1024);
    __syncthreads();

    bf16x8 af[4], wf[4];
#pragma unroll
    for (int mi = 0; mi < 4; ++mi) {
      const int row = wr * 64 + mi * 16 + lr;
      af[mi] = *(const bf16x8*)((const char*)As + row * 64 + ((g * 16) ^ swz));
    }
#pragma unroll
    for (int ni = 0; ni < 4; ++ni) {
      const int row = wc * 64 + ni * 16 + lr;
      wf[ni] = *(const bf16x8*)((const char*)Ws + row * 64 + ((g * 16) ^ swz));
    }
#pragma unroll
    for (int mi = 0; mi < 4; ++mi)
#pragma unroll
      for (int ni = 0; ni < 4; ++ni)
        acc[mi][ni] = mfma16(af[mi], wf[ni], acc[mi][ni]);
  }

#pragma unroll
  for (int mi = 0; mi < 4; ++mi)
#pragma unroll
    for (int ni = 0; ni < 4; ++ni)
#pragma unroll
      for (int r = 0; r < 4; ++r) {
        const int row = m0 + wr * 64 + mi * 16 + g * 4 + r;
        const int col = n0 + wc * 64 + ni * 16 + lr;
        C[(size_t)row * HIDDEN + col] = acc[mi][ni][r];
      }
}

// ---------------------------------------------------------------------------
// MFMA flash attention (r3 resource profile: 256 thr / 4 waves, lb (256,3),
// VGPR ~84 + 64 acc). Changes vs r3:
//  - 3-deep LDS pipeline with COUNTED vmcnt(4) + raw s_barrier (loads for
//    tiles t+1,t+2 stay in flight across the barrier; no vmcnt(0) drain)
//  - per-lane deferred l-sum (cross-lane reduce once at end)
//  - s_setprio(1) around MFMA clusters
//  - 1D grid, bid%32 = head -> all 16 q-blocks of a head on one XCD's L2
// K blocked [S/32][d/8][s%32][8], V blocked [S/8][D][8]: each 32-key tile is
// a contiguous 8KB -> 4 gll16 per wave per tile. Log2-domain, defer-max.
// ---------------------------------------------------------------------------
__global__ __launch_bounds__(256, 3) void attn_mfma(const unsigned short* __restrict__ Q,
                                                    const unsigned short* __restrict__ K,
                                                    const unsigned short* __restrict__ V,
                                                    unsigned short* __restrict__ Ab) {
  const int bid = blockIdx.x;
  const int bh = bid & 31;            // bid%8 == bh%8 -> head-aligned XCD
  const int q0 = (bid >> 5) * 128;
  const int tid = threadIdx.x;
  const int wv = tid >> 6, lane = tid & 63;
  const int g = lane >> 4, lr = lane & 15;
  const unsigned short* Qh = Q + (size_t)bh * SEQ * DH;
  const unsigned short* Kh = K + (size_t)bh * SEQ * DH;
  const unsigned short* Vh = V + (size_t)bh * SEQ * DH;

  __shared__ __align__(16) unsigned short Kls[3][4096];
  __shared__ __align__(16) unsigned short Vls[3][4096];
  __shared__ __align__(16) unsigned short Pw[4][16][40];

  bf16x8 qf[2][4];
#pragma unroll
  for (int m = 0; m < 2; ++m)
#pragma unroll
    for (int kb = 0; kb < 4; ++kb)
      qf[m][kb] = *(const bf16x8*)&Qh[(size_t)(q0 + wv * 32 + m * 16 + lr) * DH +
                                      kb * 32 + g * 8];

  f32x4 acc[2][8];
#pragma unroll
  for (int m = 0; m < 2; ++m)
#pragma unroll
    for (int dn = 0; dn < 8; ++dn) acc[m][dn] = (f32x4){0.f, 0.f, 0.f, 0.f};
  float mrun[2] = {-1e30f, -1e30f};
  float lrun[2] = {0.f, 0.f};

  // prologue: stage tiles 0 and 1 into buffers 0 and 1
#pragma unroll
  for (int tt = 0; tt < 2; ++tt)
#pragma unroll
    for (int j = 0; j < 2; ++j) {
      const int c = j * 256 + tid;
      gll16(Kh + (size_t)tt * 4096 + c * 8, (char*)&Kls[tt][0] + j * 4096 + wv * 1024);
      gll16(Vh + (size_t)tt * 4096 + c * 8, (char*)&Vls[tt][0] + j * 4096 + wv * 1024);
    }

  for (int t = 0; t < 64; ++t) {
    const int cur = t % 3;
    // tile t's 4 loads (this wave's) done; t+1/t+2 (up to 8 newer) stay in flight
    asm volatile("s_waitcnt vmcnt(4)" ::: "memory");
    __builtin_amdgcn_s_barrier();  // raw: no compiler vmcnt(0) drain
    if (t + 2 < 64) {
      const int nx = (t + 2) % 3;
      const unsigned short* Kn = Kh + (size_t)(t + 2) * 4096;
      const unsigned short* Vn = Vh + (size_t)(t + 2) * 4096;
      char* kd = (char*)&Kls[nx][0];
      char* vd = (char*)&Vls[nx][0];
#pragma unroll
      for (int j = 0; j < 2; ++j) {
        const int c = j * 256 + tid;
        gll16(Kn + (size_t)c * 8, kd + j * 4096 + wv * 1024);
        gll16(Vn + (size_t)c * 8, vd + j * 4096 + wv * 1024);
      }
    }

    const char* Kc = (const char*)&Kls[cur][0];
    const char* Vc = (const char*)&Vls[cur][0];
    bf16x8 ap[2];
#pragma unroll
    for (int m = 0; m < 2; ++m) {
      f32x4 st0 = (f32x4){0.f, 0.f, 0.f, 0.f};
      f32x4 st1 = (f32x4){0.f, 0.f, 0.f, 0.f};
      __builtin_amdgcn_s_setprio(1);
#pragma unroll
      for (int kb = 0; kb < 4; ++kb) {
        const int cb = (kb * 4 + g) * 32;
        bf16x8 kf0 = *(const bf16x8*)(Kc + (cb + lr) * 16);
        bf16x8 kf1 = *(const bf16x8*)(Kc + (cb + 16 + lr) * 16);
        st0 = mfma16(kf0, qf[m][kb], st0);
        st1 = mfma16(kf1, qf[m][kb], st1);
      }
      __builtin_amdgcn_s_setprio(0);
      float mt = fmaxf(fmaxf(fmaxf(st0[0], st0[1]), fmaxf(st0[2], st0[3])),
                       fmaxf(fmaxf(st1[0], st1[1]), fmaxf(st1[2], st1[3])));
      mt = fmaxf(mt, __shfl_xor(mt, 16));
      mt = fmaxf(mt, __shfl_xor(mt, 32));
      if (!__all(mt <= mrun[m] + 8.0f)) {  // rare rescale (defer-max)
        const float mnew = fmaxf(mrun[m], mt);
        const float corr = __builtin_amdgcn_exp2f(mrun[m] - mnew);
        lrun[m] *= corr;
        mrun[m] = mnew;
        const f32x4 cv = (f32x4){__shfl(corr, g * 4 + 0), __shfl(corr, g * 4 + 1),
                                 __shfl(corr, g * 4 + 2), __shfl(corr, g * 4 + 3)};
#pragma unroll
        for (int dn = 0; dn < 8; ++dn) acc[m][dn] *= cv;
      }
      float p[8], ls = 0.f;
#pragma unroll
      for (int r = 0; r < 4; ++r) {
        p[r] = __builtin_amdgcn_exp2f(st0[r] - mrun[m]);
        p[4 + r] = __builtin_amdgcn_exp2f(st1[r] - mrun[m]);
        ls += p[r] + p[4 + r];
      }
      lrun[m] += ls;  // per-lane partial; cross-lane reduce deferred to end
      uint2 pk0, pk1;
      pk0.x = cvtpk(p[0], p[1]); pk0.y = cvtpk(p[2], p[3]);
      pk1.x = cvtpk(p[4], p[5]); pk1.y = cvtpk(p[6], p[7]);
      *(uint2*)&Pw[wv][lr][4 * g] = pk0;
      *(uint2*)&Pw[wv][lr][16 + 4 * g] = pk1;
      ap[m] = *(const bf16x8*)&Pw[wv][lr][8 * g];
    }
    // PV
    __builtin_amdgcn_s_setprio(1);
#pragma unroll
    for (int dn = 0; dn < 8; ++dn) {
      bf16x8 vf = *(const bf16x8*)(Vc + (g * 128 + dn * 16 + lr) * 16);
      acc[0][dn] = mfma16(ap[0], vf, acc[0][dn]);
      acc[1][dn] = mfma16(ap[1], vf, acc[1][dn]);
    }
    __builtin_amdgcn_s_setprio(0);
  }

  const int b = bh >> 4, h = bh & 15;
#pragma unroll
  for (int m = 0; m < 2; ++m) {
    lrun[m] += __shfl_xor(lrun[m], 16);
    lrun[m] += __shfl_xor(lrun[m], 32);
    const float inv = 1.f / lrun[m];
    float ir[4];
#pragma unroll
    for (int r = 0; r < 4; ++r) ir[r] = __shfl(inv, g * 4 + r);
#pragma unroll
    for (int dn = 0; dn < 8; ++dn)
#pragma unroll
      for (int r = 0; r < 4; ++r) {
        const int srow = q0 + wv * 32 + m * 16 + g * 4 + r;
        Ab[((size_t)(b * SEQ + srow) * NHEADS + h) * DH + dn * 16 + lr] =
            f2bf(acc[m][dn][r] * ir[r]);
      }
  }
}

// ---------------------------------------------------------------------------
extern "C" void kernel_launch(void* const* d_in, const int* in_sizes, int n_in,
                              void* d_out, int out_size, void* d_ws,
                              size_t ws_size, hipStream_t stream) {
  const float* X  = (const float*)d_in[0];
  const float* Wq = (const float*)d_in[1];
  const float* Wk = (const float*)d_in[2];
  const float* Wv = (const float*)d_in[3];
  const float* Wo = (const float*)d_in[4];
  float* out = (float*)d_out;

  const int n1 = MTOT * HIDDEN;    // 8388608
  const int n2 = HIDDEN * HIDDEN;  // 4194304

  char* p = (char*)d_ws;
  unsigned short* Xb  = (unsigned short*)(p + 0);          // 16 MB
  unsigned short* Qb  = (unsigned short*)(p + 16777216);   // 16 MB
  unsigned short* Kb  = (unsigned short*)(p + 33554432);   // 16 MB
  unsigned short* Vb  = (unsigned short*)(p + 50331648);   // 16 MB
  unsigned short* Wqb = (unsigned short*)(p + 67108864);   // 8 MB
  unsigned short* Wkb = (unsigned short*)(p + 75497472);   // 8 MB
  unsigned short* Wvb = (unsigned short*)(p + 83886080);   // 8 MB
  unsigned short* Wob = (unsigned short*)(p + 92274688);   // 8 MB
  unsigned short* Ab  = (unsigned short*)(p + 100663296);  // 16 MB (ends 117440512)

  cast_bf16_kernel<<<n1 / 1024, 256, 0, stream>>>(X, Xb, n1);
  cast_bf16_kernel<<<n2 / 1024, 256, 0, stream>>>(Wq, Wqb, n2);
  cast_bf16_kernel<<<n2 / 1024, 256, 0, stream>>>(Wk, Wkb, n2);
  cast_bf16_kernel<<<n2 / 1024, 256, 0, stream>>>(Wv, Wvb, n2);
  cast_bf16_kernel<<<n2 / 1024, 256, 0, stream>>>(Wo, Wob, n2);

  gemm_qkv3<<<dim3(48, MTOT / 128), 256, 0, stream>>>(Xb, Wqb, Wkb, Wvb, Qb, Kb, Vb);

  attn_mfma<<<dim3(512), 256, 0, stream>>>(Qb, Kb, Vb, Ab);

  gemm_out<<<dim3(HIDDEN / 128, MTOT / 128), 256, 0, stream>>>(Ab, Wob, out);
}

// Round 7
// 287.623 us; speedup vs baseline: 1.7414x; 1.0598x over previous
//
#include <hip/hip_runtime.h>
#include <cstdint>

#define HIDDEN 2048
#define NHEADS 16
#define DH 128
#define BATCH 2
#define SEQ 2048
#define MTOT 4096
#define BH (BATCH * NHEADS)

typedef __attribute__((ext_vector_type(8))) short bf16x8;
typedef __attribute__((ext_vector_type(4))) float f32x4;

// SCALE * log2(e): scores come out of QK^T already in log2 domain
static constexpr float QSCALE = (float)(0.08838834764831845 * 1.4426950408889634);

__device__ __forceinline__ unsigned short f2bf(float f) {
  union { float f; uint32_t u; } v; v.f = f;
  uint32_t r = v.u + 0x7FFFu + ((v.u >> 16) & 1u);
  return (unsigned short)(r >> 16);
}
__device__ __forceinline__ uint32_t cvtpk(float lo, float hi) {
  uint32_t r;
  asm("v_cvt_pk_bf16_f32 %0, %1, %2" : "=v"(r) : "v"(lo), "v"(hi));
  return r;
}
__device__ __forceinline__ f32x4 mfma16(bf16x8 a, bf16x8 b, f32x4 c) {
  return __builtin_amdgcn_mfma_f32_16x16x32_bf16(a, b, c, 0, 0, 0);
}

typedef const __attribute__((address_space(1))) unsigned char* gas1_t;
typedef __attribute__((address_space(3))) unsigned char* las3_t;
__device__ __forceinline__ void gll16(const void* g, void* l) {
  __builtin_amdgcn_global_load_lds((gas1_t)g, (las3_t)l, 16, 0, 0);
}

template <int N>
__device__ __forceinline__ void waitvm() {
  if constexpr (N == 6) asm volatile("s_waitcnt vmcnt(6)" ::: "memory");
  else if constexpr (N == 3) asm volatile("s_waitcnt vmcnt(3)" ::: "memory");
  else asm volatile("s_waitcnt vmcnt(0)" ::: "memory");
}

// ---------------------------------------------------------------------------
// cast fp32 -> bf16
// ---------------------------------------------------------------------------
__global__ __launch_bounds__(256) void cast_bf16_kernel(const float* __restrict__ in,
                                                        unsigned short* __restrict__ out,
                                                        int n) {
  int i = (blockIdx.x * 256 + threadIdx.x) * 4;
  if (i < n) {
    float4 f = *(const float4*)&in[i];
    ushort4 o;
    o.x = f2bf(f.x); o.y = f2bf(f.y); o.z = f2bf(f.z); o.w = f2bf(f.w);
    *(ushort4*)&out[i] = o;
  }
}

// ---------------------------------------------------------------------------
// Deep-pipelined GEMM body (T3/T4): 4-deep LDS ring, one barrier per K-tile,
// counted vmcnt (6 steady / 3,0 tail). BM=128, BN=256, BK=32, 8 waves 2Mx4N,
// per-wave 64x64 (4x4 frags). Ring slot: A[128][32] @0 (8KB), B[256][32]
// @8192 (16KB); 24576 B/slot. Frag chunk xor ((row>>1)&3) <-> pre-swizzled
// global staging source keeps all ds_read_b128 2-way-max (free).
// Schedule per K-tile kt: waitvm -> s_barrier -> stage(kt+3) -> 8 ds_read
// -> 16 MFMA (setprio). stage after barrier makes slot (kt-1)%4 reuse safe.
// ---------------------------------------------------------------------------
template <int VM>
__device__ __forceinline__ void gemm_body(int kt, char* SM,
                                          const unsigned short* pA,
                                          const unsigned short* pB0,
                                          const unsigned short* pB1,
                                          int wv, int wr, int wc, int g, int lr,
                                          f32x4 (&acc)[4][4]) {
  waitvm<VM>();
  __builtin_amdgcn_s_barrier();
  if (kt + 3 < 64) {
    char* slot = SM + ((kt + 3) & 3) * 24576;
    const size_t ko = (size_t)(kt + 3) * 32;
    gll16(pA + ko, slot + wv * 1024);
    gll16(pB0 + ko, slot + 8192 + wv * 1024);
    gll16(pB1 + ko, slot + 16384 + wv * 1024);
  }
  const char* Ac = SM + (kt & 3) * 24576;
  const char* Bc = Ac + 8192;
  const int fx = (lr >> 1) & 3;
  bf16x8 af[4], bfr[4];
#pragma unroll
  for (int mi = 0; mi < 4; ++mi)
    af[mi] = *(const bf16x8*)(Ac + (wr * 64 + mi * 16 + lr) * 64 + ((g ^ fx) * 16));
#pragma unroll
  for (int ni = 0; ni < 4; ++ni)
    bfr[ni] = *(const bf16x8*)(Bc + (wc * 64 + ni * 16 + lr) * 64 + ((g ^ fx) * 16));
  __builtin_amdgcn_s_setprio(1);
#pragma unroll
  for (int mi = 0; mi < 4; ++mi)
#pragma unroll
    for (int ni = 0; ni < 4; ++ni)
      acc[mi][ni] = mfma16(af[mi], bfr[ni], acc[mi][ni]);
  __builtin_amdgcn_s_setprio(0);
}

// ---------------------------------------------------------------------------
// Fused Q/K/V projection, pipelined. grid (24, 32): which = x>>3, n0=(x&7)*256.
// which 0: Q [BH][S][D] (alpha=QSCALE); 1: K blocked [BH][S/32][d/8][s%32][8];
// 2: V blocked [BH][S/8][D][8].
// ---------------------------------------------------------------------------
__global__ __launch_bounds__(512) void gemm_qkv_pipe(const unsigned short* __restrict__ A,
                                                     const unsigned short* __restrict__ Wq,
                                                     const unsigned short* __restrict__ Wk,
                                                     const unsigned short* __restrict__ Wv,
                                                     unsigned short* __restrict__ Qb,
                                                     unsigned short* __restrict__ Kb,
                                                     unsigned short* __restrict__ Vb) {
  __shared__ __align__(16) char SM[98304];
  const int tid = threadIdx.x;
  const int lane = tid & 63, wv = tid >> 6;
  const int wr = wv >> 2, wc = wv & 3;
  const int g = lane >> 4, lr = lane & 15;
  const int which = blockIdx.x >> 3;
  const int m0 = blockIdx.y * 128, n0 = (blockIdx.x & 7) * 256;
  const unsigned short* W = (which == 0) ? Wq : (which == 1) ? Wk : Wv;

  const int rA = tid >> 2, cA = (tid & 3) ^ ((rA >> 1) & 3);
  const unsigned short* pA = A + (size_t)(m0 + rA) * HIDDEN + cA * 8;
  const unsigned short* pB0 = W + (size_t)(n0 + rA) * HIDDEN + cA * 8;
  const unsigned short* pB1 = W + (size_t)(n0 + 128 + rA) * HIDDEN + cA * 8;

  f32x4 acc[4][4];
#pragma unroll
  for (int i = 0; i < 4; ++i)
#pragma unroll
    for (int j = 0; j < 4; ++j) acc[i][j] = (f32x4){0.f, 0.f, 0.f, 0.f};

  // prologue: stage K-tiles 0,1,2
#pragma unroll
  for (int t = 0; t < 3; ++t) {
    char* slot = SM + t * 24576;
    gll16(pA + t * 32, slot + wv * 1024);
    gll16(pB0 + t * 32, slot + 8192 + wv * 1024);
    gll16(pB1 + t * 32, slot + 16384 + wv * 1024);
  }

  for (int kt = 0; kt < 62; ++kt)
    gemm_body<6>(kt, SM, pA, pB0, pB1, wv, wr, wc, g, lr, acc);
  gemm_body<3>(62, SM, pA, pB0, pB1, wv, wr, wc, g, lr, acc);
  gemm_body<0>(63, SM, pA, pB0, pB1, wv, wr, wc, g, lr, acc);

  const float alpha = (which == 0) ? QSCALE : 1.0f;
  unsigned short* C = (which == 0) ? Qb : (which == 1) ? Kb : Vb;
#pragma unroll
  for (int mi = 0; mi < 4; ++mi)
#pragma unroll
    for (int ni = 0; ni < 4; ++ni)
#pragma unroll
      for (int r = 0; r < 4; ++r) {
        const int row = m0 + wr * 64 + mi * 16 + g * 4 + r;
        const int col = n0 + wc * 64 + ni * 16 + lr;
        const unsigned short v = f2bf(acc[mi][ni][r] * alpha);
        const int b = row >> 11, s = row & (SEQ - 1);
        const int h = col >> 7, d = col & (DH - 1);
        const size_t base = (size_t)(b * NHEADS + h) * SEQ * DH;
        if (which == 0)
          C[base + (size_t)s * DH + d] = v;
        else if (which == 1)
          C[base + (size_t)(s >> 5) * 4096 + (d >> 3) * 256 + (s & 31) * 8 + (d & 7)] = v;
        else
          C[base + (size_t)(s >> 3) * 1024 + d * 8 + (s & 7)] = v;
      }
}

// ---------------------------------------------------------------------------
// O-projection, pipelined: C(f32)[4096][2048] = A_bf16 @ Wo_bf16^T.
// grid (8, 32): n0 = x*256, m0 = y*128.
// ---------------------------------------------------------------------------
__global__ __launch_bounds__(512) void gemm_out_pipe(const unsigned short* __restrict__ A,
                                                     const unsigned short* __restrict__ W,
                                                     float* __restrict__ C) {
  __shared__ __align__(16) char SM[98304];
  const int tid = threadIdx.x;
  const int lane = tid & 63, wv = tid >> 6;
  const int wr = wv >> 2, wc = wv & 3;
  const int g = lane >> 4, lr = lane & 15;
  const int m0 = blockIdx.y * 128, n0 = blockIdx.x * 256;

  const int rA = tid >> 2, cA = (tid & 3) ^ ((rA >> 1) & 3);
  const unsigned short* pA = A + (size_t)(m0 + rA) * HIDDEN + cA * 8;
  const unsigned short* pB0 = W + (size_t)(n0 + rA) * HIDDEN + cA * 8;
  const unsigned short* pB1 = W + (size_t)(n0 + 128 + rA) * HIDDEN + cA * 8;

  f32x4 acc[4][4];
#pragma unroll
  for (int i = 0; i < 4; ++i)
#pragma unroll
    for (int j = 0; j < 4; ++j) acc[i][j] = (f32x4){0.f, 0.f, 0.f, 0.f};

#pragma unroll
  for (int t = 0; t < 3; ++t) {
    char* slot = SM + t * 24576;
    gll16(pA + t * 32, slot + wv * 1024);
    gll16(pB0 + t * 32, slot + 8192 + wv * 1024);
    gll16(pB1 + t * 32, slot + 16384 + wv * 1024);
  }

  for (int kt = 0; kt < 62; ++kt)
    gemm_body<6>(kt, SM, pA, pB0, pB1, wv, wr, wc, g, lr, acc);
  gemm_body<3>(62, SM, pA, pB0, pB1, wv, wr, wc, g, lr, acc);
  gemm_body<0>(63, SM, pA, pB0, pB1, wv, wr, wc, g, lr, acc);

#pragma unroll
  for (int mi = 0; mi < 4; ++mi)
#pragma unroll
    for (int ni = 0; ni < 4; ++ni)
#pragma unroll
      for (int r = 0; r < 4; ++r) {
        const int row = m0 + wr * 64 + mi * 16 + g * 4 + r;
        const int col = n0 + wc * 64 + ni * 16 + lr;
        C[(size_t)row * HIDDEN + col] = acc[mi][ni][r];
      }
}

// ---------------------------------------------------------------------------
// MFMA flash attention (unchanged from round 6: 256 thr / 4 waves, 3-deep
// ring, counted vmcnt(4) + raw s_barrier, per-lane deferred l-sum, setprio,
// head-aligned XCD grid). K blocked [S/32][d/8][s%32][8], V blocked
// [S/8][D][8]. Log2-domain softmax, defer-max THR=8.
// ---------------------------------------------------------------------------
__global__ __launch_bounds__(256, 3) void attn_mfma(const unsigned short* __restrict__ Q,
                                                    const unsigned short* __restrict__ K,
                                                    const unsigned short* __restrict__ V,
                                                    unsigned short* __restrict__ Ab) {
  const int bid = blockIdx.x;
  const int bh = bid & 31;            // bid%8 == bh%8 -> head-aligned XCD
  const int q0 = (bid >> 5) * 128;
  const int tid = threadIdx.x;
  const int wv = tid >> 6, lane = tid & 63;
  const int g = lane >> 4, lr = lane & 15;
  const unsigned short* Qh = Q + (size_t)bh * SEQ * DH;
  const unsigned short* Kh = K + (size_t)bh * SEQ * DH;
  const unsigned short* Vh = V + (size_t)bh * SEQ * DH;

  __shared__ __align__(16) unsigned short Kls[3][4096];
  __shared__ __align__(16) unsigned short Vls[3][4096];
  __shared__ __align__(16) unsigned short Pw[4][16][40];

  bf16x8 qf[2][4];
#pragma unroll
  for (int m = 0; m < 2; ++m)
#pragma unroll
    for (int kb = 0; kb < 4; ++kb)
      qf[m][kb] = *(const bf16x8*)&Qh[(size_t)(q0 + wv * 32 + m * 16 + lr) * DH +
                                      kb * 32 + g * 8];

  f32x4 acc[2][8];
#pragma unroll
  for (int m = 0; m < 2; ++m)
#pragma unroll
    for (int dn = 0; dn < 8; ++dn) acc[m][dn] = (f32x4){0.f, 0.f, 0.f, 0.f};
  float mrun[2] = {-1e30f, -1e30f};
  float lrun[2] = {0.f, 0.f};

  // prologue: stage tiles 0 and 1
#pragma unroll
  for (int tt = 0; tt < 2; ++tt)
#pragma unroll
    for (int j = 0; j < 2; ++j) {
      const int c = j * 256 + tid;
      gll16(Kh + (size_t)tt * 4096 + c * 8, (char*)&Kls[tt][0] + j * 4096 + wv * 1024);
      gll16(Vh + (size_t)tt * 4096 + c * 8, (char*)&Vls[tt][0] + j * 4096 + wv * 1024);
    }

  for (int t = 0; t < 64; ++t) {
    const int cur = t % 3;
    asm volatile("s_waitcnt vmcnt(4)" ::: "memory");
    __builtin_amdgcn_s_barrier();
    if (t + 2 < 64) {
      const int nx = (t + 2) % 3;
      const unsigned short* Kn = Kh + (size_t)(t + 2) * 4096;
      const unsigned short* Vn = Vh + (size_t)(t + 2) * 4096;
      char* kd = (char*)&Kls[nx][0];
      char* vd = (char*)&Vls[nx][0];
#pragma unroll
      for (int j = 0; j < 2; ++j) {
        const int c = j * 256 + tid;
        gll16(Kn + (size_t)c * 8, kd + j * 4096 + wv * 1024);
        gll16(Vn + (size_t)c * 8, vd + j * 4096 + wv * 1024);
      }
    }

    const char* Kc = (const char*)&Kls[cur][0];
    const char* Vc = (const char*)&Vls[cur][0];
    bf16x8 ap[2];
#pragma unroll
    for (int m = 0; m < 2; ++m) {
      f32x4 st0 = (f32x4){0.f, 0.f, 0.f, 0.f};
      f32x4 st1 = (f32x4){0.f, 0.f, 0.f, 0.f};
      __builtin_amdgcn_s_setprio(1);
#pragma unroll
      for (int kb = 0; kb < 4; ++kb) {
        const int cb = (kb * 4 + g) * 32;
        bf16x8 kf0 = *(const bf16x8*)(Kc + (cb + lr) * 16);
        bf16x8 kf1 = *(const bf16x8*)(Kc + (cb + 16 + lr) * 16);
        st0 = mfma16(kf0, qf[m][kb], st0);
        st1 = mfma16(kf1, qf[m][kb], st1);
      }
      __builtin_amdgcn_s_setprio(0);
      float mt = fmaxf(fmaxf(fmaxf(st0[0], st0[1]), fmaxf(st0[2], st0[3])),
                       fmaxf(fmaxf(st1[0], st1[1]), fmaxf(st1[2], st1[3])));
      mt = fmaxf(mt, __shfl_xor(mt, 16));
      mt = fmaxf(mt, __shfl_xor(mt, 32));
      if (!__all(mt <= mrun[m] + 8.0f)) {  // rare rescale (defer-max)
        const float mnew = fmaxf(mrun[m], mt);
        const float corr = __builtin_amdgcn_exp2f(mrun[m] - mnew);
        lrun[m] *= corr;
        mrun[m] = mnew;
        const f32x4 cv = (f32x4){__shfl(corr, g * 4 + 0), __shfl(corr, g * 4 + 1),
                                 __shfl(corr, g * 4 + 2), __shfl(corr, g * 4 + 3)};
#pragma unroll
        for (int dn = 0; dn < 8; ++dn) acc[m][dn] *= cv;
      }
      float p[8], ls = 0.f;
#pragma unroll
      for (int r = 0; r < 4; ++r) {
        p[r] = __builtin_amdgcn_exp2f(st0[r] - mrun[m]);
        p[4 + r] = __builtin_amdgcn_exp2f(st1[r] - mrun[m]);
        ls += p[r] + p[4 + r];
      }
      lrun[m] += ls;  // per-lane partial; cross-lane reduce deferred to end
      uint2 pk0, pk1;
      pk0.x = cvtpk(p[0], p[1]); pk0.y = cvtpk(p[2], p[3]);
      pk1.x = cvtpk(p[4], p[5]); pk1.y = cvtpk(p[6], p[7]);
      *(uint2*)&Pw[wv][lr][4 * g] = pk0;
      *(uint2*)&Pw[wv][lr][16 + 4 * g] = pk1;
      ap[m] = *(const bf16x8*)&Pw[wv][lr][8 * g];
    }
    // PV
    __builtin_amdgcn_s_setprio(1);
#pragma unroll
    for (int dn = 0; dn < 8; ++dn) {
      bf16x8 vf = *(const bf16x8*)(Vc + (g * 128 + dn * 16 + lr) * 16);
      acc[0][dn] = mfma16(ap[0], vf, acc[0][dn]);
      acc[1][dn] = mfma16(ap[1], vf, acc[1][dn]);
    }
    __builtin_amdgcn_s_setprio(0);
  }

  const int b = bh >> 4, h = bh & 15;
#pragma unroll
  for (int m = 0; m < 2; ++m) {
    lrun[m] += __shfl_xor(lrun[m], 16);
    lrun[m] += __shfl_xor(lrun[m], 32);
    const float inv = 1.f / lrun[m];
    float ir[4];
#pragma unroll
    for (int r = 0; r < 4; ++r) ir[r] = __shfl(inv, g * 4 + r);
#pragma unroll
    for (int dn = 0; dn < 8; ++dn)
#pragma unroll
      for (int r = 0; r < 4; ++r) {
        const int srow = q0 + wv * 32 + m * 16 + g * 4 + r;
        Ab[((size_t)(b * SEQ + srow) * NHEADS + h) * DH + dn * 16 + lr] =
            f2bf(acc[m][dn][r] * ir[r]);
      }
  }
}

// ---------------------------------------------------------------------------
extern "C" void kernel_launch(void* const* d_in, const int* in_sizes, int n_in,
                              void* d_out, int out_size, void* d_ws,
                              size_t ws_size, hipStream_t stream) {
  const float* X  = (const float*)d_in[0];
  const float* Wq = (const float*)d_in[1];
  const float* Wk = (const float*)d_in[2];
  const float* Wv = (const float*)d_in[3];
  const float* Wo = (const float*)d_in[4];
  float* out = (float*)d_out;

  const int n1 = MTOT * HIDDEN;    // 8388608
  const int n2 = HIDDEN * HIDDEN;  // 4194304

  char* p = (char*)d_ws;
  unsigned short* Xb  = (unsigned short*)(p + 0);          // 16 MB
  unsigned short* Qb  = (unsigned short*)(p + 16777216);   // 16 MB
  unsigned short* Kb  = (unsigned short*)(p + 33554432);   // 16 MB
  unsigned short* Vb  = (unsigned short*)(p + 50331648);   // 16 MB
  unsigned short* Wqb = (unsigned short*)(p + 67108864);   // 8 MB
  unsigned short* Wkb = (unsigned short*)(p + 75497472);   // 8 MB
  unsigned short* Wvb = (unsigned short*)(p + 83886080);   // 8 MB
  unsigned short* Wob = (unsigned short*)(p + 92274688);   // 8 MB
  unsigned short* Ab  = (unsigned short*)(p + 100663296);  // 16 MB (ends 117440512)

  cast_bf16_kernel<<<n1 / 1024, 256, 0, stream>>>(X, Xb, n1);
  cast_bf16_kernel<<<n2 / 1024, 256, 0, stream>>>(Wq, Wqb, n2);
  cast_bf16_kernel<<<n2 / 1024, 256, 0, stream>>>(Wk, Wkb, n2);
  cast_bf16_kernel<<<n2 / 1024, 256, 0, stream>>>(Wv, Wvb, n2);
  cast_bf16_kernel<<<n2 / 1024, 256, 0, stream>>>(Wo, Wob, n2);

  gemm_qkv_pipe<<<dim3(24, MTOT / 128), 512, 0, stream>>>(Xb, Wqb, Wkb, Wvb,
                                                          Qb, Kb, Vb);

  attn_mfma<<<dim3(512), 256, 0, stream>>>(Qb, Kb, Vb, Ab);

  gemm_out_pipe<<<dim3(HIDDEN / 256, MTOT / 128), 512, 0, stream>>>(Ab, Wob, out);
}

// Round 8
// 272.731 us; speedup vs baseline: 1.8365x; 1.0546x over previous
//
#include <hip/hip_runtime.h>
#include <cstdint>

#define HIDDEN 2048
#define NHEADS 16
#define DH 128
#define BATCH 2
#define SEQ 2048
#define MTOT 4096
#define BH (BATCH * NHEADS)

typedef __attribute__((ext_vector_type(8))) short bf16x8;
typedef __attribute__((ext_vector_type(4))) float f32x4;

// SCALE * log2(e): scores come out of QK^T already in log2 domain
static constexpr float QSCALE = (float)(0.08838834764831845 * 1.4426950408889634);

__device__ __forceinline__ unsigned short f2bf(float f) {
  union { float f; uint32_t u; } v; v.f = f;
  uint32_t r = v.u + 0x7FFFu + ((v.u >> 16) & 1u);
  return (unsigned short)(r >> 16);
}
__device__ __forceinline__ uint32_t cvtpk(float lo, float hi) {
  uint32_t r;
  asm("v_cvt_pk_bf16_f32 %0, %1, %2" : "=v"(r) : "v"(lo), "v"(hi));
  return r;
}
__device__ __forceinline__ f32x4 mfma16(bf16x8 a, bf16x8 b, f32x4 c) {
  return __builtin_amdgcn_mfma_f32_16x16x32_bf16(a, b, c, 0, 0, 0);
}

typedef const __attribute__((address_space(1))) unsigned char* gas1_t;
typedef __attribute__((address_space(3))) unsigned char* las3_t;
__device__ __forceinline__ void gll16(const void* g, void* l) {
  __builtin_amdgcn_global_load_lds((gas1_t)g, (las3_t)l, 16, 0, 0);
}

template <int N>
__device__ __forceinline__ void waitvm() {
  if constexpr (N == 6) asm volatile("s_waitcnt vmcnt(6)" ::: "memory");
  else if constexpr (N == 0) asm volatile("s_waitcnt vmcnt(0)" ::: "memory");
}

// ---------------------------------------------------------------------------
// Fused cast: X (8.4M) + Wq/Wk/Wv/Wo (4.2M each), fp32 -> bf16, one launch.
// ---------------------------------------------------------------------------
__global__ __launch_bounds__(256) void cast_all(
    const float* __restrict__ X, const float* __restrict__ Wq,
    const float* __restrict__ Wk, const float* __restrict__ Wv,
    const float* __restrict__ Wo, unsigned short* __restrict__ Xb,
    unsigned short* __restrict__ Wqb, unsigned short* __restrict__ Wkb,
    unsigned short* __restrict__ Wvb, unsigned short* __restrict__ Wob) {
  const int n1 = MTOT * HIDDEN;           // 8388608
  const int i = (blockIdx.x * 256 + threadIdx.x) * 4;
  const float* s;
  unsigned short* d;
  int o;
  if (i < n1) {
    s = X; d = Xb; o = i;
  } else {
    const int j = i - n1;
    const int w = j >> 22;                 // n2 = 2^22
    o = j & ((1 << 22) - 1);
    s = (w == 0) ? Wq : (w == 1) ? Wk : (w == 2) ? Wv : Wo;
    d = (w == 0) ? Wqb : (w == 1) ? Wkb : (w == 2) ? Wvb : Wob;
  }
  float4 f = *(const float4*)&s[o];
  ushort4 u;
  u.x = f2bf(f.x); u.y = f2bf(f.y); u.z = f2bf(f.z); u.w = f2bf(f.w);
  *(ushort4*)&d[o] = u;
}

// ---------------------------------------------------------------------------
// Two-phase deep-pipelined GEMM body. BM=128, BN=256, BK=64, 512 thr / 8
// waves (2M x 4N), per-wave 64x64. 3-slot LDS ring (49152 B/slot: A 16KB @0,
// B 32KB @16384), prefetch tile kt+2. Per K-tile: 2 phases, each
// {8 ds_read_b128 -> 3 gll16 -> s_barrier -> 16 MFMA (setprio)} -> s_barrier.
// vmcnt(6) once per iter after phase-B MFMA (tail: vmcnt(0), then none).
// Chunk-XOR ch^(row&7) on 128B rows: ds_reads 2-way max (free); gll16 dest
// linear, inverse permutation applied to the per-lane GLOBAL source address.
// ---------------------------------------------------------------------------
template <int VM, bool PF>
__device__ __forceinline__ void pipe_body(
    int kt, char* SM, const unsigned short* aS0, const unsigned short* aS1,
    const unsigned short* bS0, const unsigned short* bS1,
    const unsigned short* bS2, const unsigned short* bS3, int wv, int wr,
    int wc, int g, int lr, f32x4 (&acc)[4][4]) {
  const char* Ac = SM + (kt % 3) * 49152;
  const char* Bc = Ac + 16384;
  char* slot2 = SM + ((kt + 2) % 3) * 49152;
  const size_t ko = (size_t)(kt + 2) * 64;
  const int rx = lr & 7;
  bf16x8 af[4], bfr[4];
  // ---- phase A: k-step 0 (chunks 0..3) ----
#pragma unroll
  for (int mi = 0; mi < 4; ++mi)
    af[mi] = *(const bf16x8*)(Ac + (wr * 64 + mi * 16 + lr) * 128 + ((g ^ rx) * 16));
#pragma unroll
  for (int ni = 0; ni < 4; ++ni)
    bfr[ni] = *(const bf16x8*)(Bc + (wc * 64 + ni * 16 + lr) * 128 + ((g ^ rx) * 16));
  if (PF) {
    gll16(aS0 + ko, slot2 + wv * 2048);
    gll16(aS1 + ko, slot2 + wv * 2048 + 1024);
    gll16(bS0 + ko, slot2 + 16384 + wv * 4096);
  }
  __builtin_amdgcn_s_barrier();
  __builtin_amdgcn_s_setprio(1);
#pragma unroll
  for (int mi = 0; mi < 4; ++mi)
#pragma unroll
    for (int ni = 0; ni < 4; ++ni)
      acc[mi][ni] = mfma16(af[mi], bfr[ni], acc[mi][ni]);
  __builtin_amdgcn_s_setprio(0);
  __builtin_amdgcn_s_barrier();
  // ---- phase B: k-step 1 (chunks 4..7) ----
#pragma unroll
  for (int mi = 0; mi < 4; ++mi)
    af[mi] = *(const bf16x8*)(Ac + (wr * 64 + mi * 16 + lr) * 128 + (((4 + g) ^ rx) * 16));
#pragma unroll
  for (int ni = 0; ni < 4; ++ni)
    bfr[ni] = *(const bf16x8*)(Bc + (wc * 64 + ni * 16 + lr) * 128 + (((4 + g) ^ rx) * 16));
  if (PF) {
    gll16(bS1 + ko, slot2 + 16384 + wv * 4096 + 1024);
    gll16(bS2 + ko, slot2 + 16384 + wv * 4096 + 2048);
    gll16(bS3 + ko, slot2 + 16384 + wv * 4096 + 3072);
  }
  __builtin_amdgcn_s_barrier();
  __builtin_amdgcn_s_setprio(1);
#pragma unroll
  for (int mi = 0; mi < 4; ++mi)
#pragma unroll
    for (int ni = 0; ni < 4; ++ni)
      acc[mi][ni] = mfma16(af[mi], bfr[ni], acc[mi][ni]);
  __builtin_amdgcn_s_setprio(0);
  if (VM >= 0) waitvm<VM>();
  __builtin_amdgcn_s_barrier();
}

// Per-thread staging source pointers (inverse of the LDS chunk permutation).
#define PIPE_SETUP(Abase, Bbase)                                              \
  const int idxA0 = wv * 128 + lane, idxA1 = idxA0 + 64;                      \
  const int rA0 = idxA0 >> 3, cA0 = (idxA0 & 7) ^ (rA0 & 7);                  \
  const int rA1 = idxA1 >> 3, cA1 = (idxA1 & 7) ^ (rA1 & 7);                  \
  const unsigned short* aS0 = (Abase) + (size_t)(m0 + rA0) * HIDDEN + cA0 * 8;\
  const unsigned short* aS1 = (Abase) + (size_t)(m0 + rA1) * HIDDEN + cA1 * 8;\
  const int idxB0 = wv * 256 + lane, idxB1 = idxB0 + 64,                      \
            idxB2 = idxB0 + 128, idxB3 = idxB0 + 192;                         \
  const int rB0 = idxB0 >> 3, cB0 = (idxB0 & 7) ^ (rB0 & 7);                  \
  const int rB1 = idxB1 >> 3, cB1 = (idxB1 & 7) ^ (rB1 & 7);                  \
  const int rB2 = idxB2 >> 3, cB2 = (idxB2 & 7) ^ (rB2 & 7);                  \
  const int rB3 = idxB3 >> 3, cB3 = (idxB3 & 7) ^ (rB3 & 7);                  \
  const unsigned short* bS0 = (Bbase) + (size_t)(n0 + rB0) * HIDDEN + cB0 * 8;\
  const unsigned short* bS1 = (Bbase) + (size_t)(n0 + rB1) * HIDDEN + cB1 * 8;\
  const unsigned short* bS2 = (Bbase) + (size_t)(n0 + rB2) * HIDDEN + cB2 * 8;\
  const unsigned short* bS3 = (Bbase) + (size_t)(n0 + rB3) * HIDDEN + cB3 * 8;

#define PIPE_PROLOGUE()                                                       \
  _Pragma("unroll") for (int tt = 0; tt < 2; ++tt) {                          \
    char* slot = SM + tt * 49152;                                             \
    const size_t ko = (size_t)tt * 64;                                        \
    gll16(aS0 + ko, slot + wv * 2048);                                        \
    gll16(aS1 + ko, slot + wv * 2048 + 1024);                                 \
    gll16(bS0 + ko, slot + 16384 + wv * 4096);                                \
    gll16(bS1 + ko, slot + 16384 + wv * 4096 + 1024);                         \
    gll16(bS2 + ko, slot + 16384 + wv * 4096 + 2048);                         \
    gll16(bS3 + ko, slot + 16384 + wv * 4096 + 3072);                         \
  }                                                                           \
  waitvm<6>();                                                                \
  __builtin_amdgcn_s_barrier();

#define PIPE_LOOP()                                                           \
  for (int kt = 0; kt < 30; ++kt)                                             \
    pipe_body<6, true>(kt, SM, aS0, aS1, bS0, bS1, bS2, bS3, wv, wr, wc, g,   \
                       lr, acc);                                              \
  pipe_body<0, false>(30, SM, aS0, aS1, bS0, bS1, bS2, bS3, wv, wr, wc, g,    \
                      lr, acc);                                               \
  pipe_body<-1, false>(31, SM, aS0, aS1, bS0, bS1, bS2, bS3, wv, wr, wc, g,   \
                       lr, acc);

// ---------------------------------------------------------------------------
// Fused Q/K/V projection, two-phase pipeline. grid (24, 32): which = x>>3,
// n0 = (x&7)*256 -> XCD = x%8 pins each (which,n-panel) to one XCD's L2.
// which 0: Q [BH][S][D] (alpha=QSCALE); 1: K blocked [BH][S/32][d/8][s%32][8];
// 2: V blocked [BH][S/8][D][8].
// ---------------------------------------------------------------------------
__global__ __launch_bounds__(512) void gemm_qkv_pipe(
    const unsigned short* __restrict__ A, const unsigned short* __restrict__ Wq,
    const unsigned short* __restrict__ Wk, const unsigned short* __restrict__ Wv,
    unsigned short* __restrict__ Qb, unsigned short* __restrict__ Kb,
    unsigned short* __restrict__ Vb) {
  __shared__ __align__(16) char SM[147456];
  const int tid = threadIdx.x;
  const int lane = tid & 63, wv = tid >> 6;
  const int wr = wv >> 2, wc = wv & 3;
  const int g = lane >> 4, lr = lane & 15;
  const int which = blockIdx.x >> 3;
  const int m0 = blockIdx.y * 128, n0 = (blockIdx.x & 7) * 256;
  const unsigned short* W = (which == 0) ? Wq : (which == 1) ? Wk : Wv;

  PIPE_SETUP(A, W)

  f32x4 acc[4][4];
#pragma unroll
  for (int i = 0; i < 4; ++i)
#pragma unroll
    for (int j = 0; j < 4; ++j) acc[i][j] = (f32x4){0.f, 0.f, 0.f, 0.f};

  PIPE_PROLOGUE()
  PIPE_LOOP()

  const float alpha = (which == 0) ? QSCALE : 1.0f;
  unsigned short* C = (which == 0) ? Qb : (which == 1) ? Kb : Vb;
#pragma unroll
  for (int mi = 0; mi < 4; ++mi)
#pragma unroll
    for (int ni = 0; ni < 4; ++ni)
#pragma unroll
      for (int r = 0; r < 4; ++r) {
        const int row = m0 + wr * 64 + mi * 16 + g * 4 + r;
        const int col = n0 + wc * 64 + ni * 16 + lr;
        const unsigned short v = f2bf(acc[mi][ni][r] * alpha);
        const int b = row >> 11, s = row & (SEQ - 1);
        const int h = col >> 7, d = col & (DH - 1);
        const size_t base = (size_t)(b * NHEADS + h) * SEQ * DH;
        if (which == 0)
          C[base + (size_t)s * DH + d] = v;
        else if (which == 1)
          C[base + (size_t)(s >> 5) * 4096 + (d >> 3) * 256 + (s & 31) * 8 + (d & 7)] = v;
        else
          C[base + (size_t)(s >> 3) * 1024 + d * 8 + (s & 7)] = v;
      }
}

// ---------------------------------------------------------------------------
// O-projection, two-phase pipeline: C(f32)[4096][2048] = A_bf16 @ Wo_bf16^T.
// grid (8, 32) = 256 blocks = exactly one CU round.
// ---------------------------------------------------------------------------
__global__ __launch_bounds__(512) void gemm_out_pipe(
    const unsigned short* __restrict__ A, const unsigned short* __restrict__ W,
    float* __restrict__ C) {
  __shared__ __align__(16) char SM[147456];
  const int tid = threadIdx.x;
  const int lane = tid & 63, wv = tid >> 6;
  const int wr = wv >> 2, wc = wv & 3;
  const int g = lane >> 4, lr = lane & 15;
  const int m0 = blockIdx.y * 128, n0 = blockIdx.x * 256;

  PIPE_SETUP(A, W)

  f32x4 acc[4][4];
#pragma unroll
  for (int i = 0; i < 4; ++i)
#pragma unroll
    for (int j = 0; j < 4; ++j) acc[i][j] = (f32x4){0.f, 0.f, 0.f, 0.f};

  PIPE_PROLOGUE()
  PIPE_LOOP()

#pragma unroll
  for (int mi = 0; mi < 4; ++mi)
#pragma unroll
    for (int ni = 0; ni < 4; ++ni)
#pragma unroll
      for (int r = 0; r < 4; ++r) {
        const int row = m0 + wr * 64 + mi * 16 + g * 4 + r;
        const int col = n0 + wc * 64 + ni * 16 + lr;
        C[(size_t)row * HIDDEN + col] = acc[mi][ni][r];
      }
}

// ---------------------------------------------------------------------------
// MFMA flash attention (unchanged from round 6/7: 256 thr / 4 waves, 3-deep
// ring, counted vmcnt(4) + raw s_barrier, per-lane deferred l-sum, setprio,
// head-aligned XCD grid). K blocked [S/32][d/8][s%32][8], V blocked
// [S/8][D][8]. Log2-domain softmax, defer-max THR=8.
// ---------------------------------------------------------------------------
__global__ __launch_bounds__(256, 3) void attn_mfma(const unsigned short* __restrict__ Q,
                                                    const unsigned short* __restrict__ K,
                                                    const unsigned short* __restrict__ V,
                                                    unsigned short* __restrict__ Ab) {
  const int bid = blockIdx.x;
  const int bh = bid & 31;            // bid%8 == bh%8 -> head-aligned XCD
  const int q0 = (bid >> 5) * 128;
  const int tid = threadIdx.x;
  const int wv = tid >> 6, lane = tid & 63;
  const int g = lane >> 4, lr = lane & 15;
  const unsigned short* Qh = Q + (size_t)bh * SEQ * DH;
  const unsigned short* Kh = K + (size_t)bh * SEQ * DH;
  const unsigned short* Vh = V + (size_t)bh * SEQ * DH;

  __shared__ __align__(16) unsigned short Kls[3][4096];
  __shared__ __align__(16) unsigned short Vls[3][4096];
  __shared__ __align__(16) unsigned short Pw[4][16][40];

  bf16x8 qf[2][4];
#pragma unroll
  for (int m = 0; m < 2; ++m)
#pragma unroll
    for (int kb = 0; kb < 4; ++kb)
      qf[m][kb] = *(const bf16x8*)&Qh[(size_t)(q0 + wv * 32 + m * 16 + lr) * DH +
                                      kb * 32 + g * 8];

  f32x4 acc[2][8];
#pragma unroll
  for (int m = 0; m < 2; ++m)
#pragma unroll
    for (int dn = 0; dn < 8; ++dn) acc[m][dn] = (f32x4){0.f, 0.f, 0.f, 0.f};
  float mrun[2] = {-1e30f, -1e30f};
  float lrun[2] = {0.f, 0.f};

  // prologue: stage tiles 0 and 1
#pragma unroll
  for (int tt = 0; tt < 2; ++tt)
#pragma unroll
    for (int j = 0; j < 2; ++j) {
      const int c = j * 256 + tid;
      gll16(Kh + (size_t)tt * 4096 + c * 8, (char*)&Kls[tt][0] + j * 4096 + wv * 1024);
      gll16(Vh + (size_t)tt * 4096 + c * 8, (char*)&Vls[tt][0] + j * 4096 + wv * 1024);
    }

  for (int t = 0; t < 64; ++t) {
    const int cur = t % 3;
    asm volatile("s_waitcnt vmcnt(4)" ::: "memory");
    __builtin_amdgcn_s_barrier();
    if (t + 2 < 64) {
      const int nx = (t + 2) % 3;
      const unsigned short* Kn = Kh + (size_t)(t + 2) * 4096;
      const unsigned short* Vn = Vh + (size_t)(t + 2) * 4096;
      char* kd = (char*)&Kls[nx][0];
      char* vd = (char*)&Vls[nx][0];
#pragma unroll
      for (int j = 0; j < 2; ++j) {
        const int c = j * 256 + tid;
        gll16(Kn + (size_t)c * 8, kd + j * 4096 + wv * 1024);
        gll16(Vn + (size_t)c * 8, vd + j * 4096 + wv * 1024);
      }
    }

    const char* Kc = (const char*)&Kls[cur][0];
    const char* Vc = (const char*)&Vls[cur][0];
    bf16x8 ap[2];
#pragma unroll
    for (int m = 0; m < 2; ++m) {
      f32x4 st0 = (f32x4){0.f, 0.f, 0.f, 0.f};
      f32x4 st1 = (f32x4){0.f, 0.f, 0.f, 0.f};
      __builtin_amdgcn_s_setprio(1);
#pragma unroll
      for (int kb = 0; kb < 4; ++kb) {
        const int cb = (kb * 4 + g) * 32;
        bf16x8 kf0 = *(const bf16x8*)(Kc + (cb + lr) * 16);
        bf16x8 kf1 = *(const bf16x8*)(Kc + (cb + 16 + lr) * 16);
        st0 = mfma16(kf0, qf[m][kb], st0);
        st1 = mfma16(kf1, qf[m][kb], st1);
      }
      __builtin_amdgcn_s_setprio(0);
      float mt = fmaxf(fmaxf(fmaxf(st0[0], st0[1]), fmaxf(st0[2], st0[3])),
                       fmaxf(fmaxf(st1[0], st1[1]), fmaxf(st1[2], st1[3])));
      mt = fmaxf(mt, __shfl_xor(mt, 16));
      mt = fmaxf(mt, __shfl_xor(mt, 32));
      if (!__all(mt <= mrun[m] + 8.0f)) {  // rare rescale (defer-max)
        const float mnew = fmaxf(mrun[m], mt);
        const float corr = __builtin_amdgcn_exp2f(mrun[m] - mnew);
        lrun[m] *= corr;
        mrun[m] = mnew;
        const f32x4 cv = (f32x4){__shfl(corr, g * 4 + 0), __shfl(corr, g * 4 + 1),
                                 __shfl(corr, g * 4 + 2), __shfl(corr, g * 4 + 3)};
#pragma unroll
        for (int dn = 0; dn < 8; ++dn) acc[m][dn] *= cv;
      }
      float p[8], ls = 0.f;
#pragma unroll
      for (int r = 0; r < 4; ++r) {
        p[r] = __builtin_amdgcn_exp2f(st0[r] - mrun[m]);
        p[4 + r] = __builtin_amdgcn_exp2f(st1[r] - mrun[m]);
        ls += p[r] + p[4 + r];
      }
      lrun[m] += ls;  // per-lane partial; cross-lane reduce deferred to end
      uint2 pk0, pk1;
      pk0.x = cvtpk(p[0], p[1]); pk0.y = cvtpk(p[2], p[3]);
      pk1.x = cvtpk(p[4], p[5]); pk1.y = cvtpk(p[6], p[7]);
      *(uint2*)&Pw[wv][lr][4 * g] = pk0;
      *(uint2*)&Pw[wv][lr][16 + 4 * g] = pk1;
      ap[m] = *(const bf16x8*)&Pw[wv][lr][8 * g];
    }
    // PV
    __builtin_amdgcn_s_setprio(1);
#pragma unroll
    for (int dn = 0; dn < 8; ++dn) {
      bf16x8 vf = *(const bf16x8*)(Vc + (g * 128 + dn * 16 + lr) * 16);
      acc[0][dn] = mfma16(ap[0], vf, acc[0][dn]);
      acc[1][dn] = mfma16(ap[1], vf, acc[1][dn]);
    }
    __builtin_amdgcn_s_setprio(0);
  }

  const int b = bh >> 4, h = bh & 15;
#pragma unroll
  for (int m = 0; m < 2; ++m) {
    lrun[m] += __shfl_xor(lrun[m], 16);
    lrun[m] += __shfl_xor(lrun[m], 32);
    const float inv = 1.f / lrun[m];
    float ir[4];
#pragma unroll
    for (int r = 0; r < 4; ++r) ir[r] = __shfl(inv, g * 4 + r);
#pragma unroll
    for (int dn = 0; dn < 8; ++dn)
#pragma unroll
      for (int r = 0; r < 4; ++r) {
        const int srow = q0 + wv * 32 + m * 16 + g * 4 + r;
        Ab[((size_t)(b * SEQ + srow) * NHEADS + h) * DH + dn * 16 + lr] =
            f2bf(acc[m][dn][r] * ir[r]);
      }
  }
}

// ---------------------------------------------------------------------------
extern "C" void kernel_launch(void* const* d_in, const int* in_sizes, int n_in,
                              void* d_out, int out_size, void* d_ws,
                              size_t ws_size, hipStream_t stream) {
  const float* X  = (const float*)d_in[0];
  const float* Wq = (const float*)d_in[1];
  const float* Wk = (const float*)d_in[2];
  const float* Wv = (const float*)d_in[3];
  const float* Wo = (const float*)d_in[4];
  float* out = (float*)d_out;

  const int n1 = MTOT * HIDDEN;    // 8388608
  const int n2 = HIDDEN * HIDDEN;  // 4194304

  char* p = (char*)d_ws;
  unsigned short* Xb  = (unsigned short*)(p + 0);          // 16 MB
  unsigned short* Qb  = (unsigned short*)(p + 16777216);   // 16 MB
  unsigned short* Kb  = (unsigned short*)(p + 33554432);   // 16 MB
  unsigned short* Vb  = (unsigned short*)(p + 50331648);   // 16 MB
  unsigned short* Wqb = (unsigned short*)(p + 67108864);   // 8 MB
  unsigned short* Wkb = (unsigned short*)(p + 75497472);   // 8 MB
  unsigned short* Wvb = (unsigned short*)(p + 83886080);   // 8 MB
  unsigned short* Wob = (unsigned short*)(p + 92274688);   // 8 MB
  unsigned short* Ab  = (unsigned short*)(p + 100663296);  // 16 MB (ends 117440512)

  cast_all<<<(n1 + 4 * n2) / 1024, 256, 0, stream>>>(X, Wq, Wk, Wv, Wo, Xb, Wqb,
                                                     Wkb, Wvb, Wob);

  gemm_qkv_pipe<<<dim3(24, MTOT / 128), 512, 0, stream>>>(Xb, Wqb, Wkb, Wvb,
                                                          Qb, Kb, Vb);

  attn_mfma<<<dim3(512), 256, 0, stream>>>(Qb, Kb, Vb, Ab);

  gemm_out_pipe<<<dim3(HIDDEN / 256, MTOT / 128), 512, 0, stream>>>(Ab, Wob, out);
}

// Round 9
// 270.352 us; speedup vs baseline: 1.8527x; 1.0088x over previous
//
#include <hip/hip_runtime.h>
#include <cstdint>

#define HIDDEN 2048
#define NHEADS 16
#define DH 128
#define BATCH 2
#define SEQ 2048
#define MTOT 4096
#define BH (BATCH * NHEADS)

typedef __attribute__((ext_vector_type(8))) short bf16x8;
typedef __attribute__((ext_vector_type(4))) float f32x4;

// SCALE * log2(e): scores come out of QK^T already in log2 domain
static constexpr float QSCALE = (float)(0.08838834764831845 * 1.4426950408889634);

__device__ __forceinline__ unsigned short f2bf(float f) {
  union { float f; uint32_t u; } v; v.f = f;
  uint32_t r = v.u + 0x7FFFu + ((v.u >> 16) & 1u);
  return (unsigned short)(r >> 16);
}
__device__ __forceinline__ uint32_t cvtpk(float lo, float hi) {
  uint32_t r;
  asm("v_cvt_pk_bf16_f32 %0, %1, %2" : "=v"(r) : "v"(lo), "v"(hi));
  return r;
}
__device__ __forceinline__ f32x4 mfma16(bf16x8 a, bf16x8 b, f32x4 c) {
  return __builtin_amdgcn_mfma_f32_16x16x32_bf16(a, b, c, 0, 0, 0);
}

typedef const __attribute__((address_space(1))) unsigned char* gas1_t;
typedef __attribute__((address_space(3))) unsigned char* las3_t;
__device__ __forceinline__ void gll16(const void* g, void* l) {
  __builtin_amdgcn_global_load_lds((gas1_t)g, (las3_t)l, 16, 0, 0);
}

// ---------------------------------------------------------------------------
// Fused cast: X (8.4M) + Wq/Wk/Wv/Wo (4.2M each), fp32 -> bf16, one launch.
// ---------------------------------------------------------------------------
__global__ __launch_bounds__(256) void cast_all(
    const float* __restrict__ X, const float* __restrict__ Wq,
    const float* __restrict__ Wk, const float* __restrict__ Wv,
    const float* __restrict__ Wo, unsigned short* __restrict__ Xb,
    unsigned short* __restrict__ Wqb, unsigned short* __restrict__ Wkb,
    unsigned short* __restrict__ Wvb, unsigned short* __restrict__ Wob) {
  const int n1 = MTOT * HIDDEN;           // 8388608
  const int i = (blockIdx.x * 256 + threadIdx.x) * 4;
  const float* s;
  unsigned short* d;
  int o;
  if (i < n1) {
    s = X; d = Xb; o = i;
  } else {
    const int j = i - n1;
    const int w = j >> 22;                 // n2 = 2^22
    o = j & ((1 << 22) - 1);
    s = (w == 0) ? Wq : (w == 1) ? Wk : (w == 2) ? Wv : Wo;
    d = (w == 0) ? Wqb : (w == 1) ? Wkb : (w == 2) ? Wvb : Wob;
  }
  float4 f = *(const float4*)&s[o];
  ushort4 u;
  u.x = f2bf(f.x); u.y = f2bf(f.y); u.z = f2bf(f.z); u.w = f2bf(f.w);
  *(ushort4*)&d[o] = u;
}

// ---------------------------------------------------------------------------
// Single-barrier deep-pipelined GEMM body. BM=128, BN=256, BK=64, 512 thr /
// 8 waves (2M x 4N), per-wave 64x64. 3-slot LDS ring (49152 B/slot: A 16KB
// @0, B 32KB @16384), prefetch tile kt+2. Per K-tile, ONE barrier and no
// read/MFMA phase separation: issue 8 phase-A ds_reads + 6 gll16 + 8
// phase-B ds_reads, then two 16-MFMA clusters. The compiler's
// dependency-driven lgkmcnt(8)/lgkmcnt(0) gates each cluster on exactly its
// own reads, so LDS reads of one wave overlap MFMA of another (no lockstep).
// vmcnt(6) before the barrier keeps 2 staged tiles in flight.
// Hazards: slot (kt+2)%3 overwrite is fenced by the end-of-(kt-1) barrier
// (all reads of that slot completed in iter kt-1); slot kt+1 validity by
// vmcnt(6)+barrier at end of iter kt.
// Chunk-XOR ch^(row&7) on 128B rows: ds_reads 2-way max (free); gll16 dest
// linear, inverse permutation applied to the per-lane GLOBAL source address.
// ---------------------------------------------------------------------------
template <int VM, bool PF>
__device__ __forceinline__ void pipe_body(
    int kt, char* SM, const unsigned short* aS0, const unsigned short* aS1,
    const unsigned short* bS0, const unsigned short* bS1,
    const unsigned short* bS2, const unsigned short* bS3, int wv, int wr,
    int wc, int g, int lr, f32x4 (&acc)[4][4]) {
  const char* Ac = SM + (kt % 3) * 49152;
  const char* Bc = Ac + 16384;
  char* slot2 = SM + ((kt + 2) % 3) * 49152;
  const size_t ko = (size_t)(kt + 2) * 64;
  const int rx = lr & 7;
  bf16x8 a0[4], b0[4], a1[4], b1[4];
  // phase-A fragment reads (chunk g^rx)
#pragma unroll
  for (int mi = 0; mi < 4; ++mi)
    a0[mi] = *(const bf16x8*)(Ac + (wr * 64 + mi * 16 + lr) * 128 + ((g ^ rx) * 16));
#pragma unroll
  for (int ni = 0; ni < 4; ++ni)
    b0[ni] = *(const bf16x8*)(Bc + (wc * 64 + ni * 16 + lr) * 128 + ((g ^ rx) * 16));
  // stage tile kt+2 (VMEM issued early; lands under later compute)
  if (PF) {
    gll16(aS0 + ko, slot2 + wv * 2048);
    gll16(aS1 + ko, slot2 + wv * 2048 + 1024);
    gll16(bS0 + ko, slot2 + 16384 + wv * 4096);
    gll16(bS1 + ko, slot2 + 16384 + wv * 4096 + 1024);
    gll16(bS2 + ko, slot2 + 16384 + wv * 4096 + 2048);
    gll16(bS3 + ko, slot2 + 16384 + wv * 4096 + 3072);
  }
  // phase-B fragment reads (chunk (4+g)^rx)
#pragma unroll
  for (int mi = 0; mi < 4; ++mi)
    a1[mi] = *(const bf16x8*)(Ac + (wr * 64 + mi * 16 + lr) * 128 + (((4 + g) ^ rx) * 16));
#pragma unroll
  for (int ni = 0; ni < 4; ++ni)
    b1[ni] = *(const bf16x8*)(Bc + (wc * 64 + ni * 16 + lr) * 128 + (((4 + g) ^ rx) * 16));
  __builtin_amdgcn_s_setprio(1);
#pragma unroll
  for (int mi = 0; mi < 4; ++mi)
#pragma unroll
    for (int ni = 0; ni < 4; ++ni)
      acc[mi][ni] = mfma16(a0[mi], b0[ni], acc[mi][ni]);
#pragma unroll
  for (int mi = 0; mi < 4; ++mi)
#pragma unroll
    for (int ni = 0; ni < 4; ++ni)
      acc[mi][ni] = mfma16(a1[mi], b1[ni], acc[mi][ni]);
  __builtin_amdgcn_s_setprio(0);
  if (VM == 6) asm volatile("s_waitcnt vmcnt(6)" ::: "memory");
  else if (VM == 0) asm volatile("s_waitcnt vmcnt(0)" ::: "memory");
  if (VM >= 0) __builtin_amdgcn_s_barrier();
}

// Per-thread staging source pointers (inverse of the LDS chunk permutation).
#define PIPE_SETUP(Abase, Bbase)                                              \
  const int idxA0 = wv * 128 + lane, idxA1 = idxA0 + 64;                      \
  const int rA0 = idxA0 >> 3, cA0 = (idxA0 & 7) ^ (rA0 & 7);                  \
  const int rA1 = idxA1 >> 3, cA1 = (idxA1 & 7) ^ (rA1 & 7);                  \
  const unsigned short* aS0 = (Abase) + (size_t)(m0 + rA0) * HIDDEN + cA0 * 8;\
  const unsigned short* aS1 = (Abase) + (size_t)(m0 + rA1) * HIDDEN + cA1 * 8;\
  const int idxB0 = wv * 256 + lane, idxB1 = idxB0 + 64,                      \
            idxB2 = idxB0 + 128, idxB3 = idxB0 + 192;                         \
  const int rB0 = idxB0 >> 3, cB0 = (idxB0 & 7) ^ (rB0 & 7);                  \
  const int rB1 = idxB1 >> 3, cB1 = (idxB1 & 7) ^ (rB1 & 7);                  \
  const int rB2 = idxB2 >> 3, cB2 = (idxB2 & 7) ^ (rB2 & 7);                  \
  const int rB3 = idxB3 >> 3, cB3 = (idxB3 & 7) ^ (rB3 & 7);                  \
  const unsigned short* bS0 = (Bbase) + (size_t)(n0 + rB0) * HIDDEN + cB0 * 8;\
  const unsigned short* bS1 = (Bbase) + (size_t)(n0 + rB1) * HIDDEN + cB1 * 8;\
  const unsigned short* bS2 = (Bbase) + (size_t)(n0 + rB2) * HIDDEN + cB2 * 8;\
  const unsigned short* bS3 = (Bbase) + (size_t)(n0 + rB3) * HIDDEN + cB3 * 8;

#define PIPE_PROLOGUE()                                                       \
  _Pragma("unroll") for (int tt = 0; tt < 2; ++tt) {                          \
    char* slot = SM + tt * 49152;                                             \
    const size_t ko = (size_t)tt * 64;                                        \
    gll16(aS0 + ko, slot + wv * 2048);                                        \
    gll16(aS1 + ko, slot + wv * 2048 + 1024);                                 \
    gll16(bS0 + ko, slot + 16384 + wv * 4096);                                \
    gll16(bS1 + ko, slot + 16384 + wv * 4096 + 1024);                         \
    gll16(bS2 + ko, slot + 16384 + wv * 4096 + 2048);                         \
    gll16(bS3 + ko, slot + 16384 + wv * 4096 + 3072);                         \
  }                                                                           \
  asm volatile("s_waitcnt vmcnt(6)" ::: "memory");                            \
  __builtin_amdgcn_s_barrier();

#define PIPE_LOOP()                                                           \
  for (int kt = 0; kt < 30; ++kt)                                             \
    pipe_body<6, true>(kt, SM, aS0, aS1, bS0, bS1, bS2, bS3, wv, wr, wc, g,   \
                       lr, acc);                                              \
  pipe_body<0, false>(30, SM, aS0, aS1, bS0, bS1, bS2, bS3, wv, wr, wc, g,    \
                      lr, acc);                                               \
  pipe_body<-1, false>(31, SM, aS0, aS1, bS0, bS1, bS2, bS3, wv, wr, wc, g,   \
                       lr, acc);

// ---------------------------------------------------------------------------
// Fused Q/K/V projection. grid (24, 32): which = x>>3, n0 = (x&7)*256 ->
// XCD = x%8 pins each (which,n-panel) to one XCD's L2.
// which 0: Q [BH][S][D] (alpha=QSCALE); 1: K blocked [BH][S/32][d/8][s%32][8];
// 2: V blocked [BH][S/8][D][8].
// ---------------------------------------------------------------------------
__global__ __launch_bounds__(512) void gemm_qkv_pipe(
    const unsigned short* __restrict__ A, const unsigned short* __restrict__ Wq,
    const unsigned short* __restrict__ Wk, const unsigned short* __restrict__ Wv,
    unsigned short* __restrict__ Qb, unsigned short* __restrict__ Kb,
    unsigned short* __restrict__ Vb) {
  __shared__ __align__(16) char SM[147456];
  const int tid = threadIdx.x;
  const int lane = tid & 63, wv = tid >> 6;
  const int wr = wv >> 2, wc = wv & 3;
  const int g = lane >> 4, lr = lane & 15;
  const int which = blockIdx.x >> 3;
  const int m0 = blockIdx.y * 128, n0 = (blockIdx.x & 7) * 256;
  const unsigned short* W = (which == 0) ? Wq : (which == 1) ? Wk : Wv;

  PIPE_SETUP(A, W)

  f32x4 acc[4][4];
#pragma unroll
  for (int i = 0; i < 4; ++i)
#pragma unroll
    for (int j = 0; j < 4; ++j) acc[i][j] = (f32x4){0.f, 0.f, 0.f, 0.f};

  PIPE_PROLOGUE()
  PIPE_LOOP()

  const float alpha = (which == 0) ? QSCALE : 1.0f;
  unsigned short* C = (which == 0) ? Qb : (which == 1) ? Kb : Vb;
#pragma unroll
  for (int mi = 0; mi < 4; ++mi)
#pragma unroll
    for (int ni = 0; ni < 4; ++ni)
#pragma unroll
      for (int r = 0; r < 4; ++r) {
        const int row = m0 + wr * 64 + mi * 16 + g * 4 + r;
        const int col = n0 + wc * 64 + ni * 16 + lr;
        const unsigned short v = f2bf(acc[mi][ni][r] * alpha);
        const int b = row >> 11, s = row & (SEQ - 1);
        const int h = col >> 7, d = col & (DH - 1);
        const size_t base = (size_t)(b * NHEADS + h) * SEQ * DH;
        if (which == 0)
          C[base + (size_t)s * DH + d] = v;
        else if (which == 1)
          C[base + (size_t)(s >> 5) * 4096 + (d >> 3) * 256 + (s & 31) * 8 + (d & 7)] = v;
        else
          C[base + (size_t)(s >> 3) * 1024 + d * 8 + (s & 7)] = v;
      }
}

// ---------------------------------------------------------------------------
// O-projection: C(f32)[4096][2048] = A_bf16 @ Wo_bf16^T.
// grid (8, 32) = 256 blocks = exactly one CU round.
// ---------------------------------------------------------------------------
__global__ __launch_bounds__(512) void gemm_out_pipe(
    const unsigned short* __restrict__ A, const unsigned short* __restrict__ W,
    float* __restrict__ C) {
  __shared__ __align__(16) char SM[147456];
  const int tid = threadIdx.x;
  const int lane = tid & 63, wv = tid >> 6;
  const int wr = wv >> 2, wc = wv & 3;
  const int g = lane >> 4, lr = lane & 15;
  const int m0 = blockIdx.y * 128, n0 = blockIdx.x * 256;

  PIPE_SETUP(A, W)

  f32x4 acc[4][4];
#pragma unroll
  for (int i = 0; i < 4; ++i)
#pragma unroll
    for (int j = 0; j < 4; ++j) acc[i][j] = (f32x4){0.f, 0.f, 0.f, 0.f};

  PIPE_PROLOGUE()
  PIPE_LOOP()

#pragma unroll
  for (int mi = 0; mi < 4; ++mi)
#pragma unroll
    for (int ni = 0; ni < 4; ++ni)
#pragma unroll
      for (int r = 0; r < 4; ++r) {
        const int row = m0 + wr * 64 + mi * 16 + g * 4 + r;
        const int col = n0 + wc * 64 + ni * 16 + lr;
        C[(size_t)row * HIDDEN + col] = acc[mi][ni][r];
      }
}

// ---------------------------------------------------------------------------
// MFMA flash attention (unchanged from round 6-8: 256 thr / 4 waves, 3-deep
// ring, counted vmcnt(4) + raw s_barrier, per-lane deferred l-sum, setprio,
// head-aligned XCD grid). K blocked [S/32][d/8][s%32][8], V blocked
// [S/8][D][8]. Log2-domain softmax, defer-max THR=8.
// ---------------------------------------------------------------------------
__global__ __launch_bounds__(256, 3) void attn_mfma(const unsigned short* __restrict__ Q,
                                                    const unsigned short* __restrict__ K,
                                                    const unsigned short* __restrict__ V,
                                                    unsigned short* __restrict__ Ab) {
  const int bid = blockIdx.x;
  const int bh = bid & 31;            // bid%8 == bh%8 -> head-aligned XCD
  const int q0 = (bid >> 5) * 128;
  const int tid = threadIdx.x;
  const int wv = tid >> 6, lane = tid & 63;
  const int g = lane >> 4, lr = lane & 15;
  const unsigned short* Qh = Q + (size_t)bh * SEQ * DH;
  const unsigned short* Kh = K + (size_t)bh * SEQ * DH;
  const unsigned short* Vh = V + (size_t)bh * SEQ * DH;

  __shared__ __align__(16) unsigned short Kls[3][4096];
  __shared__ __align__(16) unsigned short Vls[3][4096];
  __shared__ __align__(16) unsigned short Pw[4][16][40];

  bf16x8 qf[2][4];
#pragma unroll
  for (int m = 0; m < 2; ++m)
#pragma unroll
    for (int kb = 0; kb < 4; ++kb)
      qf[m][kb] = *(const bf16x8*)&Qh[(size_t)(q0 + wv * 32 + m * 16 + lr) * DH +
                                      kb * 32 + g * 8];

  f32x4 acc[2][8];
#pragma unroll
  for (int m = 0; m < 2; ++m)
#pragma unroll
    for (int dn = 0; dn < 8; ++dn) acc[m][dn] = (f32x4){0.f, 0.f, 0.f, 0.f};
  float mrun[2] = {-1e30f, -1e30f};
  float lrun[2] = {0.f, 0.f};

  // prologue: stage tiles 0 and 1
#pragma unroll
  for (int tt = 0; tt < 2; ++tt)
#pragma unroll
    for (int j = 0; j < 2; ++j) {
      const int c = j * 256 + tid;
      gll16(Kh + (size_t)tt * 4096 + c * 8, (char*)&Kls[tt][0] + j * 4096 + wv * 1024);
      gll16(Vh + (size_t)tt * 4096 + c * 8, (char*)&Vls[tt][0] + j * 4096 + wv * 1024);
    }

  for (int t = 0; t < 64; ++t) {
    const int cur = t % 3;
    asm volatile("s_waitcnt vmcnt(4)" ::: "memory");
    __builtin_amdgcn_s_barrier();
    if (t + 2 < 64) {
      const int nx = (t + 2) % 3;
      const unsigned short* Kn = Kh + (size_t)(t + 2) * 4096;
      const unsigned short* Vn = Vh + (size_t)(t + 2) * 4096;
      char* kd = (char*)&Kls[nx][0];
      char* vd = (char*)&Vls[nx][0];
#pragma unroll
      for (int j = 0; j < 2; ++j) {
        const int c = j * 256 + tid;
        gll16(Kn + (size_t)c * 8, kd + j * 4096 + wv * 1024);
        gll16(Vn + (size_t)c * 8, vd + j * 4096 + wv * 1024);
      }
    }

    const char* Kc = (const char*)&Kls[cur][0];
    const char* Vc = (const char*)&Vls[cur][0];
    bf16x8 ap[2];
#pragma unroll
    for (int m = 0; m < 2; ++m) {
      f32x4 st0 = (f32x4){0.f, 0.f, 0.f, 0.f};
      f32x4 st1 = (f32x4){0.f, 0.f, 0.f, 0.f};
      __builtin_amdgcn_s_setprio(1);
#pragma unroll
      for (int kb = 0; kb < 4; ++kb) {
        const int cb = (kb * 4 + g) * 32;
        bf16x8 kf0 = *(const bf16x8*)(Kc + (cb + lr) * 16);
        bf16x8 kf1 = *(const bf16x8*)(Kc + (cb + 16 + lr) * 16);
        st0 = mfma16(kf0, qf[m][kb], st0);
        st1 = mfma16(kf1, qf[m][kb], st1);
      }
      __builtin_amdgcn_s_setprio(0);
      float mt = fmaxf(fmaxf(fmaxf(st0[0], st0[1]), fmaxf(st0[2], st0[3])),
                       fmaxf(fmaxf(st1[0], st1[1]), fmaxf(st1[2], st1[3])));
      mt = fmaxf(mt, __shfl_xor(mt, 16));
      mt = fmaxf(mt, __shfl_xor(mt, 32));
      if (!__all(mt <= mrun[m] + 8.0f)) {  // rare rescale (defer-max)
        const float mnew = fmaxf(mrun[m], mt);
        const float corr = __builtin_amdgcn_exp2f(mrun[m] - mnew);
        lrun[m] *= corr;
        mrun[m] = mnew;
        const f32x4 cv = (f32x4){__shfl(corr, g * 4 + 0), __shfl(corr, g * 4 + 1),
                                 __shfl(corr, g * 4 + 2), __shfl(corr, g * 4 + 3)};
#pragma unroll
        for (int dn = 0; dn < 8; ++dn) acc[m][dn] *= cv;
      }
      float p[8], ls = 0.f;
#pragma unroll
      for (int r = 0; r < 4; ++r) {
        p[r] = __builtin_amdgcn_exp2f(st0[r] - mrun[m]);
        p[4 + r] = __builtin_amdgcn_exp2f(st1[r] - mrun[m]);
        ls += p[r] + p[4 + r];
      }
      lrun[m] += ls;  // per-lane partial; cross-lane reduce deferred to end
      uint2 pk0, pk1;
      pk0.x = cvtpk(p[0], p[1]); pk0.y = cvtpk(p[2], p[3]);
      pk1.x = cvtpk(p[4], p[5]); pk1.y = cvtpk(p[6], p[7]);
      *(uint2*)&Pw[wv][lr][4 * g] = pk0;
      *(uint2*)&Pw[wv][lr][16 + 4 * g] = pk1;
      ap[m] = *(const bf16x8*)&Pw[wv][lr][8 * g];
    }
    // PV
    __builtin_amdgcn_s_setprio(1);
#pragma unroll
    for (int dn = 0; dn < 8; ++dn) {
      bf16x8 vf = *(const bf16x8*)(Vc + (g * 128 + dn * 16 + lr) * 16);
      acc[0][dn] = mfma16(ap[0], vf, acc[0][dn]);
      acc[1][dn] = mfma16(ap[1], vf, acc[1][dn]);
    }
    __builtin_amdgcn_s_setprio(0);
  }

  const int b = bh >> 4, h = bh & 15;
#pragma unroll
  for (int m = 0; m < 2; ++m) {
    lrun[m] += __shfl_xor(lrun[m], 16);
    lrun[m] += __shfl_xor(lrun[m], 32);
    const float inv = 1.f / lrun[m];
    float ir[4];
#pragma unroll
    for (int r = 0; r < 4; ++r) ir[r] = __shfl(inv, g * 4 + r);
#pragma unroll
    for (int dn = 0; dn < 8; ++dn)
#pragma unroll
      for (int r = 0; r < 4; ++r) {
        const int srow = q0 + wv * 32 + m * 16 + g * 4 + r;
        Ab[((size_t)(b * SEQ + srow) * NHEADS + h) * DH + dn * 16 + lr] =
            f2bf(acc[m][dn][r] * ir[r]);
      }
  }
}

// ---------------------------------------------------------------------------
extern "C" void kernel_launch(void* const* d_in, const int* in_sizes, int n_in,
                              void* d_out, int out_size, void* d_ws,
                              size_t ws_size, hipStream_t stream) {
  const float* X  = (const float*)d_in[0];
  const float* Wq = (const float*)d_in[1];
  const float* Wk = (const float*)d_in[2];
  const float* Wv = (const float*)d_in[3];
  const float* Wo = (const float*)d_in[4];
  float* out = (float*)d_out;

  const int n1 = MTOT * HIDDEN;    // 8388608
  const int n2 = HIDDEN * HIDDEN;  // 4194304

  char* p = (char*)d_ws;
  unsigned short* Xb  = (unsigned short*)(p + 0);          // 16 MB
  unsigned short* Qb  = (unsigned short*)(p + 16777216);   // 16 MB
  unsigned short* Kb  = (unsigned short*)(p + 33554432);   // 16 MB
  unsigned short* Vb  = (unsigned short*)(p + 50331648);   // 16 MB
  unsigned short* Wqb = (unsigned short*)(p + 67108864);   // 8 MB
  unsigned short* Wkb = (unsigned short*)(p + 75497472);   // 8 MB
  unsigned short* Wvb = (unsigned short*)(p + 83886080);   // 8 MB
  unsigned short* Wob = (unsigned short*)(p + 92274688);   // 8 MB
  unsigned short* Ab  = (unsigned short*)(p + 100663296);  // 16 MB (ends 117440512)

  cast_all<<<(n1 + 4 * n2) / 1024, 256, 0, stream>>>(X, Wq, Wk, Wv, Wo, Xb, Wqb,
                                                     Wkb, Wvb, Wob);

  gemm_qkv_pipe<<<dim3(24, MTOT / 128), 512, 0, stream>>>(Xb, Wqb, Wkb, Wvb,
                                                          Qb, Kb, Vb);

  attn_mfma<<<dim3(512), 256, 0, stream>>>(Qb, Kb, Vb, Ab);

  gemm_out_pipe<<<dim3(HIDDEN / 256, MTOT / 128), 512, 0, stream>>>(Ab, Wob, out);
}